// Round 2
// baseline (275.160 us; speedup 1.0000x reference)
//
#include <hip/hip_runtime.h>
#include <hip/hip_bf16.h>
#include <stdint.h>

// R11: (a) 6 -> 4 dispatches: k1 = featT | weff1 | bias-eff, k2 = w2-reduce |
// IoU-max, k3 = conv, k4 = loss + last-block finalize (k_fin folded in via
// atomic counter). (b) k_conv: 4x8 = 32 spatial tiles -> 512 blocks = 2
// blocks/CU (LDS 108.5 KB -> 77.8 KB): w2 records packed 80 B -> 64 B with an
// XOR quad-swizzle baked into the GLOBAL w2 layout (gl_lds stages linearly;
// reader applies the same XOR), sF tiles shrunk to <=15x9 pos. XCD-swizzled
// blockIdx (512 % 8 == 0 -> bijective) for featT2 L2 locality.

using bf16x8 = __attribute__((ext_vector_type(8))) __bf16;
using f32x4  = __attribute__((ext_vector_type(4))) float;

// featT2 layout (CHUNK-MAJOR): featT2[chunk 16][img 16][pos 52*52][64 B].
// pos = i*52+j, row/col 0,51 = zero borders. All data bytes written every call
// by the featT role (interior tiles + border tile); no memset.
#define FT_CHUNK_STRIDE 2768896   // 16 img * 2704 pos * 64 B
// W2 layout (R11, PACKED+SWIZZLED): [ci-chunk 16][tap 9][cf 3][rec 16][64 B].
// rec = co&15 within cf block; the 4 ci-quads (16 B each) of record r are
// stored at slot (q ^ (r&3)) so the A-fragment ds_read spreads banks.
#define W2_CHUNK_B 27648

// ---------- helpers ----------
__device__ __forceinline__ unsigned short f2bf(float f) {
  union { float f; unsigned u; } x; x.f = f;
  unsigned r = x.u + 0x7fffu + ((x.u >> 16) & 1u);   // RNE
  return (unsigned short)(r >> 16);
}

__device__ __forceinline__ void gl_lds16(const void* g, void* l) {
  __builtin_amdgcn_global_load_lds(
      (const __attribute__((address_space(1))) void*)g,
      (__attribute__((address_space(3))) void*)l, 16, 0, 0);
}

__device__ __forceinline__ float sl1(float d) {
  float ad = fabsf(d);
  return ad < 1.f ? 0.5f * d * d : ad - 0.5f;
}
__device__ __forceinline__ float softplus_f(float x) {
  return fmaxf(x, 0.f) + log1pf(expf(-fabsf(x)));
}

// strict-fp anchor + IoU: identical bits in the iou-max pass and k_loss (no
// contraction possible through __f*_rn intrinsics) so (iou == max) is exact.
__device__ __forceinline__ void anchor_strict(int n, float& ax1, float& ay1,
                                              float& ax2, float& ay2) {
  int ii = n / 450;
  int rem = n - ii * 450;
  int jj = rem / 9;
  int a  = rem - jj * 9;
  const float SC[3] = {2.f, 4.f, 6.f};
  const float RA[3] = {0.5f, 1.f, 1.5f};
  float w = __fmul_rn(SC[a % 3], RA[a / 3]);
  float h = SC[a % 3];
  float cx = __fadd_rn((float)ii, 0.5f);
  float cy = __fadd_rn((float)jj, 0.5f);
  float wh = __fmul_rn(w, 0.5f), hh = __fmul_rn(h, 0.5f);
  ax1 = fminf(fmaxf(__fsub_rn(cx, wh), 0.f), 50.f);
  ax2 = fminf(fmaxf(__fadd_rn(cx, wh), 0.f), 50.f);
  ay1 = fminf(fmaxf(__fsub_rn(cy, hh), 0.f), 50.f);
  ay2 = fminf(fmaxf(__fadd_rn(cy, hh), 0.f), 50.f);
}
__device__ __forceinline__ float iou_strict(float ax1, float ay1, float ax2, float ay2,
                                            float aarea, const float* __restrict__ g) {
  float gx1 = __fmul_rn(g[0], 0.0625f), gy1 = __fmul_rn(g[1], 0.0625f);
  float gx2 = __fmul_rn(g[2], 0.0625f), gy2 = __fmul_rn(g[3], 0.0625f);
  float ix1 = fmaxf(ax1, gx1), iy1 = fmaxf(ay1, gy1);
  float ix2 = fminf(ax2, gx2), iy2 = fminf(ay2, gy2);
  float inter = __fmul_rn(fmaxf(__fsub_rn(ix2, ix1), 0.f),
                          fmaxf(__fsub_rn(iy2, iy1), 0.f));
  float garea = __fmul_rn(__fsub_rn(gx2, gx1), __fsub_rn(gy2, gy1));
  float denom = __fadd_rn(__fsub_rn(__fadd_rn(aarea, garea), inter), 1e-8f);
  return __fdiv_rn(inter, denom);
}

// ---------- k1: featT (blocks 0..1343) | weff1 (1344..1487) | bias (1488..1535)
// featT: features NCHW fp32 -> chunk-major packed bf16 (LDS transpose).
// weff1: part[cz][co 48][kmem 4608] = sum_{outC in cz} whead[co][outC]*w1[outC][kmem]
// bias:  bias_eff[co] = b_head[co] + whead[co]·b1
__global__ __launch_bounds__(256) void k1(const float* __restrict__ feat,
                                          char* __restrict__ featT2,
                                          const float* __restrict__ w1,
                                          const float* __restrict__ wc,
                                          const float* __restrict__ wb,
                                          const float* __restrict__ b1,
                                          const float* __restrict__ bc,
                                          const float* __restrict__ bbx,
                                          float* __restrict__ part,
                                          float* __restrict__ bias_eff,
                                          unsigned* __restrict__ zbuf) {
  __shared__ __align__(16) char smem[128 * 132 * 2];   // featT sT / weff1 sW union
  const int bxr = blockIdx.x;
  const int tid = threadIdx.x;

  if (bxr >= 1488) {                 // ---- bias-eff role ----
    int co = bxr - 1488;
    int l = tid;
    if (l >= 64) return;
    float s = 0.f;
#pragma unroll
    for (int q = 0; q < 8; ++q) {
      int c = q * 64 + l;
      float wv = co < 9 ? wc[co * 512 + c] : (co < 45 ? wb[(co - 9) * 512 + c] : 0.f);
      s += wv * b1[c];
    }
    for (int o = 32; o; o >>= 1) s += __shfl_down(s, o, 64);
    if (l == 0)
      bias_eff[co] = s + (co < 9 ? bc[co] : (co < 45 ? bbx[co - 9] : 0.f));
    return;
  }

  if (bxr >= 1344) {                 // ---- weff1 role (256 threads) ----
    int bx2 = bxr - 1344;            // 0..143 = [cz 8][kx 18]
    if (bx2 == 0) {                  // zero mx(256)+accum(8) dwords
      if (tid < 264) zbuf[tid] = 0u;  // wait: 264 > 256 -> second element below
      if (tid < 8) zbuf[256 + tid] = 0u;
    }
    int cz = bx2 / 18, kx = bx2 - cz * 18;
    float* sW = (float*)smem;        // [48][64]
    const int kmem = kx * 256 + tid;
#pragma unroll
    for (int q = 0; q < 12; ++q) {
      int idx = tid + q * 256;
      int co = idx >> 6, cl = idx & 63;
      int c = cz * 64 + cl;
      float v = 0.f;
      if (co < 9) v = wc[co * 512 + c];
      else if (co < 45) v = wb[(co - 9) * 512 + c];
      sW[co * 64 + cl] = v;
    }
    __syncthreads();
    float acc[48];
#pragma unroll
    for (int co = 0; co < 48; ++co) acc[co] = 0.f;
    const float* w1p = w1 + (size_t)(cz * 64) * 4608 + kmem;
    for (int c4 = 0; c4 < 64; c4 += 4) {
      float f0 = w1p[(size_t)(c4 + 0) * 4608];
      float f1 = w1p[(size_t)(c4 + 1) * 4608];
      float f2 = w1p[(size_t)(c4 + 2) * 4608];
      float f3 = w1p[(size_t)(c4 + 3) * 4608];
#pragma unroll
      for (int co = 0; co < 48; ++co) {
        float4 wv = *(const float4*)&sW[co * 64 + c4];
        acc[co] += wv.x * f0 + wv.y * f1 + wv.z * f2 + wv.w * f3;
      }
    }
    float* dst = part + (size_t)cz * 221184 + kmem;
#pragma unroll
    for (int co = 0; co < 48; ++co) dst[(size_t)co * 4608] = acc[co];
    return;
  }

  // ---- featT role ----
  const int tile = bxr % 21;
  const int rest = bxr / 21;
  const int g    = rest & 3;              // ci group: chunks g*4..g*4+3
  const int b    = rest >> 2;
  if (tile == 20) {                       // border: zero 204 positions' chunks
    uint4 z = {0, 0, 0, 0};
    for (int u = tid; u < 204 * 4; u += 256) {
      int p = u & 255; if (p >= 204) p -= 204;     // u%204 without div
      int c4 = u / 204;
      int ip, jp;
      if (p < 52)       { ip = 0;       jp = p; }
      else if (p < 104) { ip = 51;      jp = p - 52; }
      else if (p < 154) { ip = p - 103; jp = 0; }
      else              { ip = p - 153; jp = 51; }
      char* dst = featT2 + (size_t)(g * 4 + c4) * FT_CHUNK_STRIDE
                + (size_t)(b * 2704 + ip * 52 + jp) * 64;
      *(uint4*)(dst)      = z;
      *(uint4*)(dst + 16) = z;
      *(uint4*)(dst + 32) = z;
      *(uint4*)(dst + 48) = z;
    }
    return;
  }
  unsigned short* sT = (unsigned short*)smem;      // [128][132]
  const int pos0 = tile * 128;
  const float* fb = feat + (size_t)b * 1280000 + (size_t)(g * 128) * 2500;
  const int pq = tid & 31;                // pos quad: pos0 + pq*4 .. +3
  const int rg = tid >> 5;                // ci row-group (4 rows), 0..7
  const int p  = pos0 + pq * 4;
#pragma unroll
  for (int it = 0; it < 4; ++it) {
    int cb = it * 32 + rg * 4;            // ci within group
    float vv[4][4];
#pragma unroll
    for (int q = 0; q < 4; ++q) {
      const float* src = fb + (size_t)(cb + q) * 2500 + p;
      if (p + 3 < 2500) {
        float4 v = *(const float4*)src;
        vv[q][0] = v.x; vv[q][1] = v.y; vv[q][2] = v.z; vv[q][3] = v.w;
      } else {
#pragma unroll
        for (int e = 0; e < 4; ++e)
          vv[q][e] = fb[(size_t)(cb + q) * 2500 + min(p + e, 2499)];
      }
    }
#pragma unroll
    for (int pp = 0; pp < 4; ++pp) {
      ushort4 pk;
      pk.x = f2bf(vv[0][pp]); pk.y = f2bf(vv[1][pp]);
      pk.z = f2bf(vv[2][pp]); pk.w = f2bf(vv[3][pp]);
      *(ushort4*)&sT[(pq * 4 + pp) * 132 + cb] = pk;
    }
  }
  __syncthreads();
#pragma unroll
  for (int q2 = 0; q2 < 2; ++q2) {
    int u = tid + q2 * 256;
    int ch = u >> 7, pr = u & 127;        // consecutive threads -> consecutive pos
    int gp = pos0 + pr;
    if (gp >= 2500) continue;
    int i = gp / 50, j = gp - i * 50;
    char* dst = featT2 + (size_t)(g * 4 + ch) * FT_CHUNK_STRIDE
              + (size_t)(b * 2704 + (i + 1) * 52 + (j + 1)) * 64;
    const uint4* src = (const uint4*)&sT[pr * 132 + ch * 32];
    uint4 a0 = src[0], a1 = src[1], a2 = src[2], a3 = src[3];
    *(uint4*)(dst)      = a0;
    *(uint4*)(dst + 16) = a1;
    *(uint4*)(dst + 32) = a2;
    *(uint4*)(dst + 48) = a3;
  }
}

// ---------- k2: blocks <864: reduce partials -> packed/swizzled W2;
//                blocks >=864: per-(b,gt) max IoU ----------
__global__ __launch_bounds__(256) void k2(const float* __restrict__ part,
                                          unsigned short* __restrict__ w2,
                                          const float* __restrict__ gt_boxes,
                                          unsigned* __restrict__ mx) {
  if (blockIdx.x >= 864) {                   // IoU max pass
    int q = blockIdx.x - 864;                // 0..1407
    int b = q / 88, nb = q - b * 88;
    int n = nb * 256 + threadIdx.x;
    float lm[16];
#pragma unroll
    for (int m = 0; m < 16; ++m) lm[m] = 0.f;
    if (n < 22500) {
      float ax1, ay1, ax2, ay2;
      anchor_strict(n, ax1, ay1, ax2, ay2);
      float aarea = __fmul_rn(__fsub_rn(ax2, ax1), __fsub_rn(ay2, ay1));
#pragma unroll
      for (int m = 0; m < 16; ++m)
        lm[m] = iou_strict(ax1, ay1, ax2, ay2, aarea, gt_boxes + (b * 16 + m) * 4);
    }
    __shared__ float red[4][16];
#pragma unroll
    for (int m = 0; m < 16; ++m) {
      float v = lm[m];
      for (int o = 32; o; o >>= 1) v = fmaxf(v, __shfl_down(v, o, 64));
      if ((threadIdx.x & 63) == 0) red[threadIdx.x >> 6][m] = v;
    }
    __syncthreads();
    if (threadIdx.x < 16) {
      float v = fmaxf(fmaxf(red[0][threadIdx.x], red[1][threadIdx.x]),
                      fmaxf(red[2][threadIdx.x], red[3][threadIdx.x]));
      atomicMax(mx + b * 16 + threadIdx.x, __float_as_uint(v));
    }
    return;
  }
  // W2 reduce: 864*256 = 221184 = 16 chunks * 9 taps * 48 co * 32 e
  int idx = blockIdx.x * 256 + threadIdx.x;
  int c = idx / 13824;  int r = idx - c * 13824;
  int tap = r / 1536;   int r2 = r - tap * 1536;
  int co = r2 >> 5;     int e = r2 & 31;
  int ci = c * 32 + e;
  const float* p = part + (size_t)co * 4608 + ci * 9 + tap;
  float s = 0.f;
#pragma unroll
  for (int cz = 0; cz < 8; ++cz) s += p[(size_t)cz * 221184];
  // packed 64-B record, quad q stored at slot q ^ (rec&3)
  int boff = c * W2_CHUNK_B + tap * 3072 + (co >> 4) * 1024 + (co & 15) * 64
           + ((((e >> 3) ^ co) & 3) << 4) + ((e & 7) << 1);
  w2[boff >> 1] = f2bf(s);
}

// ---------- k3: direct conv+head: 4x8 spatial tiles, 2 blocks/CU ----------
__global__ __launch_bounds__(256, 2) void k3(const char* __restrict__ featT2,
                                             const char* __restrict__ w2g,
                                             const float* __restrict__ beff,
                                             float* __restrict__ oh) {
  __shared__ __align__(16) char sF[2][11264];   // <=135 pos * 80 B; 11*1024 staged
  __shared__ __align__(16) char sA[2][27648];   // 9 taps * 3 cf * 16 rec * 64 B
  const int tid = threadIdx.x, lane = tid & 63, w = tid >> 6;
  // XCD-aware swizzle (512 % 8 == 0 -> bijective): XCD x runs images 2x,2x+1.
  const int bx0 = blockIdx.x;
  const int bx = ((bx0 & 7) << 6) | (bx0 >> 3);
  const int b = bx >> 5, tl = bx & 31, tr = tl >> 3, tc = tl & 7;
  const int i0 = tr * 13 - (tr == 3 ? 1 : 0);       // {0,13,26,38}
  const int TI = (tr >= 2) ? 12 : 13;
  const int TJ = (tc < 2) ? 7 : 6;                  // 7+7+6*6 = 50
  const int j0 = (tc < 2) ? tc * 7 : 14 + (tc - 2) * 6;
  const int TJ2 = TJ + 2;
  const int mcount = TI * TJ;                       // <= 91
  const int pieces = (TI + 2) * TJ2 * 5;            // <= 675 16-B pieces/chunk

  // sF staging: piece pi -> (pos, pc); pc==4 is the LDS pad piece (dup of 3).
  const char* srcF[3];
#pragma unroll
  for (int k = 0; k < 3; ++k) {
    int s = w * 3 + k;
    int pi = s * 64 + lane;
    if (pi >= pieces) pi = pieces - 1;
    int pos = pi / 5, pc = pi - pos * 5;
    if (pc > 3) pc = 3;
    int hi = pos / TJ2, hj = pos - hi * TJ2;
    srcF[k] = featT2 + (size_t)(b * 2704 + (i0 + hi) * 52 + (j0 + hj)) * 64 + pc * 16;
  }
  int idxB[2];
#pragma unroll
  for (int bf = 0; bf < 2; ++bf) {
    int p = (w * 2 + bf) * 16 + (lane & 15);
    if (p >= mcount) p = mcount - 1;
    int di = p / TJ, dj = p - di * TJ;
    idxB[bf] = (di * TJ2 + dj) * 80 + (lane >> 4) * 16;
  }
  // A-fragment LDS offset: rec=lane&15, quad slot = (lane>>4) ^ (lane&3)
  const int aoff = (lane & 15) * 64 + ((((lane >> 4) ^ lane) & 3) << 4);
  int toff[9];
#pragma unroll
  for (int tp = 0; tp < 9; ++tp) toff[tp] = ((tp / 3) * TJ2 + (tp % 3)) * 80;

  f32x4 acc[3][2] = {};

  auto stage = [&](int c, int pb) {
    size_t coff = (size_t)c * FT_CHUNK_STRIDE;
#pragma unroll
    for (int k = 0; k < 3; ++k) {
      int s = w * 3 + k;
      if (s < 11) gl_lds16(srcF[k] + coff, sF[pb] + s * 1024);
    }
#pragma unroll
    for (int k = 0; k < 7; ++k) {
      int s = w + 4 * k;
      if (s < 27)
        gl_lds16(w2g + (size_t)c * W2_CHUNK_B + s * 1024 + lane * 16, sA[pb] + s * 1024);
    }
  };

  stage(0, 0);
  __builtin_amdgcn_s_waitcnt(0);
  __syncthreads();

  for (int c = 0; c < 16; ++c) {
    int pb = c & 1;
    if (c < 15) stage(c + 1, pb ^ 1);
    const char* fA = sA[pb];
    const char* fB = sF[pb];
#pragma unroll
    for (int tp = 0; tp < 9; ++tp) {
      bf16x8 av[3], bv[2];
#pragma unroll
      for (int cf = 0; cf < 3; ++cf)
        av[cf] = *(const bf16x8*)(fA + tp * 3072 + cf * 1024 + aoff);
#pragma unroll
      for (int bf = 0; bf < 2; ++bf)
        bv[bf] = *(const bf16x8*)(fB + idxB[bf] + toff[tp]);
#pragma unroll
      for (int cf = 0; cf < 3; ++cf)
#pragma unroll
        for (int bf = 0; bf < 2; ++bf)
          acc[cf][bf] = __builtin_amdgcn_mfma_f32_16x16x32_bf16(av[cf], bv[bf], acc[cf][bf], 0, 0, 0);
    }
    __builtin_amdgcn_s_waitcnt(0);
    __syncthreads();
  }

  f32x4 bias[3];
#pragma unroll
  for (int cf = 0; cf < 3; ++cf)
    bias[cf] = *(const f32x4*)(beff + cf * 16 + (lane >> 4) * 4);
#pragma unroll
  for (int bf = 0; bf < 2; ++bf) {
    int p = (w * 2 + bf) * 16 + (lane & 15);
    if (p >= mcount) continue;
    int di = p / TJ, dj = p - di * TJ;
    int gm = (b * 50 + i0 + di) * 50 + (j0 + dj);
#pragma unroll
    for (int cf = 0; cf < 3; ++cf) {
      f32x4 v = acc[cf][bf];
#pragma unroll
      for (int r = 0; r < 4; ++r) v[r] += bias[cf][r];
      *(f32x4*)(oh + (size_t)gm * 48 + cf * 16 + (lane >> 4) * 4) = v;
    }
  }
}

// ---------- k4: loss pass + last-block finalize ----------
__global__ __launch_bounds__(256) void k4(const float* __restrict__ gt_boxes,
                                          const unsigned* __restrict__ mxbuf,
                                          const float* __restrict__ oh,
                                          float* __restrict__ accum,
                                          float* __restrict__ dout) {
  int b = blockIdx.y;
  int n = blockIdx.x * 256 + threadIdx.x;
  float s_np = 0.f, s_reg = 0.f, s_pos = 0.f, s_nc = 0.f, s_nl = 0.f;
  if (n < 22500) {
    float ax1, ay1, ax2, ay2;
    anchor_strict(n, ax1, ay1, ax2, ay2);
    float aarea = __fmul_rn(__fsub_rn(ax2, ax1), __fsub_rn(ay2, ay1));
    float acx = (ax1 + ax2) * 0.5f, acy = (ay1 + ay2) * 0.5f;
    float aw = fmaxf(ax2 - ax1, 1e-6f), ah = fmaxf(ay2 - ay1, 1e-6f);
    int ii = n / 450, rem = n - ii * 450, jj = rem / 9, a = rem - jj * 9;
    const float* row = oh + ((size_t)(b * 2500 + ii * 50 + jj)) * 48;
    float logit = row[a];
    float p0 = row[9 + a * 4], p1 = row[10 + a * 4];
    float p2 = row[11 + a * 4], p3 = row[12 + a * 4];
    int npos = 0;
    bool allneg = true;
#pragma unroll
    for (int m = 0; m < 16; ++m) {
      const float* g = gt_boxes + (b * 16 + m) * 4;
      float iou = iou_strict(ax1, ay1, ax2, ay2, aarea, g);
      float mxv = __uint_as_float(mxbuf[b * 16 + m]);
      bool pos = ((iou == mxv) && (mxv > 0.f)) || (iou > 0.7f);
      if (iou >= 0.3f) allneg = false;
      if (pos) {
        ++npos;
        float gx1 = g[0] * 0.0625f, gy1 = g[1] * 0.0625f;
        float gx2 = g[2] * 0.0625f, gy2 = g[3] * 0.0625f;
        float gcx = (gx1 + gx2) * 0.5f, gcy = (gy1 + gy2) * 0.5f;
        float gw = fmaxf(gx2 - gx1, 1e-6f), gh = fmaxf(gy2 - gy1, 1e-6f);
        float tx = (gcx - acx) / aw, ty = (gcy - acy) / ah;
        float twv = logf(gw / aw), thv = logf(gh / ah);
        s_reg += sl1(tx - p0) + sl1(ty - p1) + sl1(twv - p2) + sl1(thv - p3);
      }
    }
    s_np = (float)npos;
    s_pos = (float)npos * softplus_f(-logit);
    if (allneg) { s_nc = 1.f; s_nl = softplus_f(logit); }
    float pcx = acx + p0 * aw, pcy = acy + p1 * ah;
    float pw = aw * expf(p2), ph = ah * expf(p3);
    float* o = dout + 1 + ((size_t)b * 22500 + n) * 4;
    o[0] = pcx - pw * 0.5f;
    o[1] = pcy - ph * 0.5f;
    o[2] = pcx + pw * 0.5f;
    o[3] = pcy + ph * 0.5f;
  }
  float vals[5] = {s_np, s_reg, s_pos, s_nc, s_nl};
  __shared__ float red[4][5];
#pragma unroll
  for (int q = 0; q < 5; ++q) {
    float v = vals[q];
    for (int o = 32; o; o >>= 1) v += __shfl_down(v, o, 64);
    if ((threadIdx.x & 63) == 0) red[threadIdx.x >> 6][q] = v;
  }
  __syncthreads();
  if (threadIdx.x < 5) {
    float v = red[0][threadIdx.x] + red[1][threadIdx.x] +
              red[2][threadIdx.x] + red[3][threadIdx.x];
    atomicAdd(accum + threadIdx.x, v);
  }
  // last-block finalize (replaces k_fin): counter at accum[5], zeroed by k1.
  __syncthreads();                    // drains this block's atomics (vmcnt 0)
  if (threadIdx.x == 0) {
    __threadfence();
    unsigned old = atomicAdd((unsigned*)(accum + 5), 1u);
    if (old == 1407u) {               // 88*16 = 1408 blocks
      float np = fmaxf(atomicAdd(accum + 0, 0.f), 1.f);
      float rg = atomicAdd(accum + 1, 0.f);
      float pp = atomicAdd(accum + 2, 0.f);
      float nn = fmaxf(atomicAdd(accum + 3, 0.f), 1.f);
      float nl = atomicAdd(accum + 4, 0.f);
      dout[0] = 0.5f * (pp / np + nl / nn) + 5.f * (rg / (4.f * np));
    }
  }
}

// ---------- launch ----------
extern "C" void kernel_launch(void* const* d_in, const int* in_sizes, int n_in,
                              void* d_out, int out_size, void* d_ws, size_t ws_size,
                              hipStream_t stream) {
  const float* features = (const float*)d_in[0];
  const float* gt_boxes = (const float*)d_in[1];
  const float* w1    = (const float*)d_in[2];
  const float* b1    = (const float*)d_in[3];
  const float* w_cls = (const float*)d_in[4];
  const float* b_cls = (const float*)d_in[5];
  const float* w_box = (const float*)d_in[6];
  const float* b_box = (const float*)d_in[7];
  float* out = (float*)d_out;
  char* ws = (char*)d_ws;

  // ws layout (featT2 chunk-major: 16*16*2704*64 = 44,302,336 B)
  char*           featT2 = ws;                                  // 44,302,336 B
  unsigned short* w2     = (unsigned short*)(ws + 44302336);    //    442,368 B used
  float*          wpart  = (float*)(ws + 44855296);             //  7,077,888 B
  float*          oh     = (float*)(ws + 51933184);             //  7,680,000 B
  float*          beff   = (float*)(ws + 59613184);             //        192 B
  unsigned*       mx     = (unsigned*)(ws + 59613376);          //      1,024 B
  float*          accum  = (float*)(ws + 59614400);             //         32 B

  k1<<<1536, 256, 0, stream>>>(features, featT2, w1, w_cls, w_box, b1, b_cls,
                               b_box, wpart, beff, mx);
  k2<<<2272, 256, 0, stream>>>(wpart, w2, gt_boxes, mx);
  k3<<<512, 256, 0, stream>>>(featT2, (const char*)w2, beff, oh);
  k4<<<dim3(88, 16), 256, 0, stream>>>(gt_boxes, mx, oh, accum, out);
}

// Round 3
// 259.553 us; speedup vs baseline: 1.0601x; 1.0601x over previous
//
#include <hip/hip_runtime.h>
#include <hip/hip_bf16.h>
#include <stdint.h>

// R12: fix R11's k1 regression. (a) k1 gets __launch_bounds__(256,4): 16
// waves/CU floor -> <=128 VGPR -> weff1's acc[48] no longer spills to scratch
// (R11 reported 52 VGPR = spill => 70 us, 1.5 TB/s, 9% VALU). (b) role order
// flipped: weff1 blocks 0..143 + bias 144..191 launch FIRST (resident in
// dispatch round 0, overlap featT) instead of forming a serial tail.
// (c) k2 W2-reduce re-indexed so a wave reads 1 KB contiguous per cz slice
// (was 36-B-strided lanes = 8x over-fetch). Same cz sum order -> bit-identical.

using bf16x8 = __attribute__((ext_vector_type(8))) __bf16;
using f32x4  = __attribute__((ext_vector_type(4))) float;

// featT2 layout (CHUNK-MAJOR): featT2[chunk 16][img 16][pos 52*52][64 B].
// pos = i*52+j, row/col 0,51 = zero borders. All data bytes written every call
// by the featT role (interior tiles + border tile); no memset.
#define FT_CHUNK_STRIDE 2768896   // 16 img * 2704 pos * 64 B
// W2 layout (PACKED+SWIZZLED): [ci-chunk 16][tap 9][cf 3][rec 16][64 B].
// rec = co&15 within cf block; the 4 ci-quads (16 B each) of record r are
// stored at slot (q ^ (r&3)) so the A-fragment ds_read spreads banks.
#define W2_CHUNK_B 27648

// ---------- helpers ----------
__device__ __forceinline__ unsigned short f2bf(float f) {
  union { float f; unsigned u; } x; x.f = f;
  unsigned r = x.u + 0x7fffu + ((x.u >> 16) & 1u);   // RNE
  return (unsigned short)(r >> 16);
}

__device__ __forceinline__ void gl_lds16(const void* g, void* l) {
  __builtin_amdgcn_global_load_lds(
      (const __attribute__((address_space(1))) void*)g,
      (__attribute__((address_space(3))) void*)l, 16, 0, 0);
}

__device__ __forceinline__ float sl1(float d) {
  float ad = fabsf(d);
  return ad < 1.f ? 0.5f * d * d : ad - 0.5f;
}
__device__ __forceinline__ float softplus_f(float x) {
  return fmaxf(x, 0.f) + log1pf(expf(-fabsf(x)));
}

// strict-fp anchor + IoU: identical bits in the iou-max pass and k_loss (no
// contraction possible through __f*_rn intrinsics) so (iou == max) is exact.
__device__ __forceinline__ void anchor_strict(int n, float& ax1, float& ay1,
                                              float& ax2, float& ay2) {
  int ii = n / 450;
  int rem = n - ii * 450;
  int jj = rem / 9;
  int a  = rem - jj * 9;
  const float SC[3] = {2.f, 4.f, 6.f};
  const float RA[3] = {0.5f, 1.f, 1.5f};
  float w = __fmul_rn(SC[a % 3], RA[a / 3]);
  float h = SC[a % 3];
  float cx = __fadd_rn((float)ii, 0.5f);
  float cy = __fadd_rn((float)jj, 0.5f);
  float wh = __fmul_rn(w, 0.5f), hh = __fmul_rn(h, 0.5f);
  ax1 = fminf(fmaxf(__fsub_rn(cx, wh), 0.f), 50.f);
  ax2 = fminf(fmaxf(__fadd_rn(cx, wh), 0.f), 50.f);
  ay1 = fminf(fmaxf(__fsub_rn(cy, hh), 0.f), 50.f);
  ay2 = fminf(fmaxf(__fadd_rn(cy, hh), 0.f), 50.f);
}
__device__ __forceinline__ float iou_strict(float ax1, float ay1, float ax2, float ay2,
                                            float aarea, const float* __restrict__ g) {
  float gx1 = __fmul_rn(g[0], 0.0625f), gy1 = __fmul_rn(g[1], 0.0625f);
  float gx2 = __fmul_rn(g[2], 0.0625f), gy2 = __fmul_rn(g[3], 0.0625f);
  float ix1 = fmaxf(ax1, gx1), iy1 = fmaxf(ay1, gy1);
  float ix2 = fminf(ax2, gx2), iy2 = fminf(ay2, gy2);
  float inter = __fmul_rn(fmaxf(__fsub_rn(ix2, ix1), 0.f),
                          fmaxf(__fsub_rn(iy2, iy1), 0.f));
  float garea = __fmul_rn(__fsub_rn(gx2, gx1), __fsub_rn(gy2, gy1));
  float denom = __fadd_rn(__fsub_rn(__fadd_rn(aarea, garea), inter), 1e-8f);
  return __fdiv_rn(inter, denom);
}

// ---------- k1: weff1 (blocks 0..143) | bias (144..191) | featT (192..1535)
// weff1: part[cz][co 48][kmem 4608] = sum_{outC in cz} whead[co][outC]*w1[outC][kmem]
// bias:  bias_eff[co] = b_head[co] + whead[co]·b1
// featT: features NCHW fp32 -> chunk-major packed bf16 (LDS transpose).
__global__ __launch_bounds__(256, 4) void k1(const float* __restrict__ feat,
                                             char* __restrict__ featT2,
                                             const float* __restrict__ w1,
                                             const float* __restrict__ wc,
                                             const float* __restrict__ wb,
                                             const float* __restrict__ b1,
                                             const float* __restrict__ bc,
                                             const float* __restrict__ bbx,
                                             float* __restrict__ part,
                                             float* __restrict__ bias_eff,
                                             unsigned* __restrict__ zbuf) {
  __shared__ __align__(16) char smem[128 * 132 * 2];   // featT sT / weff1 sW union
  const int bxr = blockIdx.x;
  const int tid = threadIdx.x;

  if (bxr < 144) {                   // ---- weff1 role (256 threads) ----
    int bx2 = bxr;                   // 0..143 = [cz 8][kx 18]
    if (bx2 == 0) {                  // zero mx(256)+accum(8) dwords
      if (tid < 256) zbuf[tid] = 0u;
      if (tid < 8) zbuf[256 + tid] = 0u;
    }
    int cz = bx2 / 18, kx = bx2 - cz * 18;
    float* sW = (float*)smem;        // [48][64]
    const int kmem = kx * 256 + tid;
#pragma unroll
    for (int q = 0; q < 12; ++q) {
      int idx = tid + q * 256;
      int co = idx >> 6, cl = idx & 63;
      int c = cz * 64 + cl;
      float v = 0.f;
      if (co < 9) v = wc[co * 512 + c];
      else if (co < 45) v = wb[(co - 9) * 512 + c];
      sW[co * 64 + cl] = v;
    }
    __syncthreads();
    float acc[48];
#pragma unroll
    for (int co = 0; co < 48; ++co) acc[co] = 0.f;
    const float* w1p = w1 + (size_t)(cz * 64) * 4608 + kmem;
    for (int c4 = 0; c4 < 64; c4 += 4) {
      float f0 = w1p[(size_t)(c4 + 0) * 4608];
      float f1 = w1p[(size_t)(c4 + 1) * 4608];
      float f2 = w1p[(size_t)(c4 + 2) * 4608];
      float f3 = w1p[(size_t)(c4 + 3) * 4608];
#pragma unroll
      for (int co = 0; co < 48; ++co) {
        float4 wv = *(const float4*)&sW[co * 64 + c4];
        acc[co] += wv.x * f0 + wv.y * f1 + wv.z * f2 + wv.w * f3;
      }
    }
    float* dst = part + (size_t)cz * 221184 + kmem;
#pragma unroll
    for (int co = 0; co < 48; ++co) dst[(size_t)co * 4608] = acc[co];
    return;
  }

  if (bxr < 192) {                   // ---- bias-eff role ----
    int co = bxr - 144;
    int l = tid;
    if (l >= 64) return;
    float s = 0.f;
#pragma unroll
    for (int q = 0; q < 8; ++q) {
      int c = q * 64 + l;
      float wv = co < 9 ? wc[co * 512 + c] : (co < 45 ? wb[(co - 9) * 512 + c] : 0.f);
      s += wv * b1[c];
    }
    for (int o = 32; o; o >>= 1) s += __shfl_down(s, o, 64);
    if (l == 0)
      bias_eff[co] = s + (co < 9 ? bc[co] : (co < 45 ? bbx[co - 9] : 0.f));
    return;
  }

  // ---- featT role ----
  const int bxr2 = bxr - 192;             // 0..1343
  const int tile = bxr2 % 21;
  const int rest = bxr2 / 21;
  const int g    = rest & 3;              // ci group: chunks g*4..g*4+3
  const int b    = rest >> 2;
  if (tile == 20) {                       // border: zero 204 positions' chunks
    uint4 z = {0, 0, 0, 0};
    for (int u = tid; u < 204 * 4; u += 256) {
      int p = u & 255; if (p >= 204) p -= 204;     // u%204 without div
      int c4 = u / 204;
      int ip, jp;
      if (p < 52)       { ip = 0;       jp = p; }
      else if (p < 104) { ip = 51;      jp = p - 52; }
      else if (p < 154) { ip = p - 103; jp = 0; }
      else              { ip = p - 153; jp = 51; }
      char* dst = featT2 + (size_t)(g * 4 + c4) * FT_CHUNK_STRIDE
                + (size_t)(b * 2704 + ip * 52 + jp) * 64;
      *(uint4*)(dst)      = z;
      *(uint4*)(dst + 16) = z;
      *(uint4*)(dst + 32) = z;
      *(uint4*)(dst + 48) = z;
    }
    return;
  }
  unsigned short* sT = (unsigned short*)smem;      // [128][132]
  const int pos0 = tile * 128;
  const float* fb = feat + (size_t)b * 1280000 + (size_t)(g * 128) * 2500;
  const int pq = tid & 31;                // pos quad: pos0 + pq*4 .. +3
  const int rg = tid >> 5;                // ci row-group (4 rows), 0..7
  const int p  = pos0 + pq * 4;
#pragma unroll
  for (int it = 0; it < 4; ++it) {
    int cb = it * 32 + rg * 4;            // ci within group
    float vv[4][4];
#pragma unroll
    for (int q = 0; q < 4; ++q) {
      const float* src = fb + (size_t)(cb + q) * 2500 + p;
      if (p + 3 < 2500) {
        float4 v = *(const float4*)src;
        vv[q][0] = v.x; vv[q][1] = v.y; vv[q][2] = v.z; vv[q][3] = v.w;
      } else {
#pragma unroll
        for (int e = 0; e < 4; ++e)
          vv[q][e] = fb[(size_t)(cb + q) * 2500 + min(p + e, 2499)];
      }
    }
#pragma unroll
    for (int pp = 0; pp < 4; ++pp) {
      ushort4 pk;
      pk.x = f2bf(vv[0][pp]); pk.y = f2bf(vv[1][pp]);
      pk.z = f2bf(vv[2][pp]); pk.w = f2bf(vv[3][pp]);
      *(ushort4*)&sT[(pq * 4 + pp) * 132 + cb] = pk;
    }
  }
  __syncthreads();
#pragma unroll
  for (int q2 = 0; q2 < 2; ++q2) {
    int u = tid + q2 * 256;
    int ch = u >> 7, pr = u & 127;        // consecutive threads -> consecutive pos
    int gp = pos0 + pr;
    if (gp >= 2500) continue;
    int i = gp / 50, j = gp - i * 50;
    char* dst = featT2 + (size_t)(g * 4 + ch) * FT_CHUNK_STRIDE
              + (size_t)(b * 2704 + (i + 1) * 52 + (j + 1)) * 64;
    const uint4* src = (const uint4*)&sT[pr * 132 + ch * 32];
    uint4 a0 = src[0], a1 = src[1], a2 = src[2], a3 = src[3];
    *(uint4*)(dst)      = a0;
    *(uint4*)(dst + 16) = a1;
    *(uint4*)(dst + 32) = a2;
    *(uint4*)(dst + 48) = a3;
  }
}

// ---------- k2: blocks <864: reduce partials -> packed/swizzled W2 (coalesced);
//                blocks >=864: per-(b,gt) max IoU ----------
__global__ __launch_bounds__(256) void k2(const float* __restrict__ part,
                                          unsigned short* __restrict__ w2,
                                          const float* __restrict__ gt_boxes,
                                          unsigned* __restrict__ mx) {
  if (blockIdx.x >= 864) {                   // IoU max pass
    int q = blockIdx.x - 864;                // 0..1407
    int b = q / 88, nb = q - b * 88;
    int n = nb * 256 + threadIdx.x;
    float lm[16];
#pragma unroll
    for (int m = 0; m < 16; ++m) lm[m] = 0.f;
    if (n < 22500) {
      float ax1, ay1, ax2, ay2;
      anchor_strict(n, ax1, ay1, ax2, ay2);
      float aarea = __fmul_rn(__fsub_rn(ax2, ax1), __fsub_rn(ay2, ay1));
#pragma unroll
      for (int m = 0; m < 16; ++m)
        lm[m] = iou_strict(ax1, ay1, ax2, ay2, aarea, gt_boxes + (b * 16 + m) * 4);
    }
    __shared__ float red[4][16];
#pragma unroll
    for (int m = 0; m < 16; ++m) {
      float v = lm[m];
      for (int o = 32; o; o >>= 1) v = fmaxf(v, __shfl_down(v, o, 64));
      if ((threadIdx.x & 63) == 0) red[threadIdx.x >> 6][m] = v;
    }
    __syncthreads();
    if (threadIdx.x < 16) {
      float v = fmaxf(fmaxf(red[0][threadIdx.x], red[1][threadIdx.x]),
                      fmaxf(red[2][threadIdx.x], red[3][threadIdx.x]));
      atomicMax(mx + b * 16 + threadIdx.x, __float_as_uint(v));
    }
    return;
  }
  // W2 reduce, COALESCED: 864 = 48 co * 18 kx; thread -> kmem = kx*256+tid.
  // Wave reads 1 KB contiguous per cz slice (part[cz][co][kmem], kmem-major).
  int co = blockIdx.x / 18, kx = blockIdx.x - co * 18;
  int kmem = kx * 256 + threadIdx.x;       // 0..4607
  const float* p = part + (size_t)co * 4608 + kmem;
  float s = 0.f;
#pragma unroll
  for (int cz = 0; cz < 8; ++cz) s += p[(size_t)cz * 221184];
  int ci = kmem / 9, tap = kmem - ci * 9;
  int c = ci >> 5, e = ci & 31;
  // packed 64-B record, quad q stored at slot q ^ (rec&3)
  int boff = c * W2_CHUNK_B + tap * 3072 + (co >> 4) * 1024 + (co & 15) * 64
           + ((((e >> 3) ^ co) & 3) << 4) + ((e & 7) << 1);
  w2[boff >> 1] = f2bf(s);
}

// ---------- k3: direct conv+head: 4x8 spatial tiles, 2 blocks/CU ----------
__global__ __launch_bounds__(256, 2) void k3(const char* __restrict__ featT2,
                                             const char* __restrict__ w2g,
                                             const float* __restrict__ beff,
                                             float* __restrict__ oh) {
  __shared__ __align__(16) char sF[2][11264];   // <=135 pos * 80 B; 11*1024 staged
  __shared__ __align__(16) char sA[2][27648];   // 9 taps * 3 cf * 16 rec * 64 B
  const int tid = threadIdx.x, lane = tid & 63, w = tid >> 6;
  // XCD-aware swizzle (512 % 8 == 0 -> bijective): XCD x runs images 2x,2x+1.
  const int bx0 = blockIdx.x;
  const int bx = ((bx0 & 7) << 6) | (bx0 >> 3);
  const int b = bx >> 5, tl = bx & 31, tr = tl >> 3, tc = tl & 7;
  const int i0 = tr * 13 - (tr == 3 ? 1 : 0);       // {0,13,26,38}
  const int TI = (tr >= 2) ? 12 : 13;
  const int TJ = (tc < 2) ? 7 : 6;                  // 7+7+6*6 = 50
  const int j0 = (tc < 2) ? tc * 7 : 14 + (tc - 2) * 6;
  const int TJ2 = TJ + 2;
  const int mcount = TI * TJ;                       // <= 91
  const int pieces = (TI + 2) * TJ2 * 5;            // <= 675 16-B pieces/chunk

  // sF staging: piece pi -> (pos, pc); pc==4 is the LDS pad piece (dup of 3).
  const char* srcF[3];
#pragma unroll
  for (int k = 0; k < 3; ++k) {
    int s = w * 3 + k;
    int pi = s * 64 + lane;
    if (pi >= pieces) pi = pieces - 1;
    int pos = pi / 5, pc = pi - pos * 5;
    if (pc > 3) pc = 3;
    int hi = pos / TJ2, hj = pos - hi * TJ2;
    srcF[k] = featT2 + (size_t)(b * 2704 + (i0 + hi) * 52 + (j0 + hj)) * 64 + pc * 16;
  }
  int idxB[2];
#pragma unroll
  for (int bf = 0; bf < 2; ++bf) {
    int p = (w * 2 + bf) * 16 + (lane & 15);
    if (p >= mcount) p = mcount - 1;
    int di = p / TJ, dj = p - di * TJ;
    idxB[bf] = (di * TJ2 + dj) * 80 + (lane >> 4) * 16;
  }
  // A-fragment LDS offset: rec=lane&15, quad slot = (lane>>4) ^ (lane&3)
  const int aoff = (lane & 15) * 64 + ((((lane >> 4) ^ lane) & 3) << 4);
  int toff[9];
#pragma unroll
  for (int tp = 0; tp < 9; ++tp) toff[tp] = ((tp / 3) * TJ2 + (tp % 3)) * 80;

  f32x4 acc[3][2] = {};

  auto stage = [&](int c, int pb) {
    size_t coff = (size_t)c * FT_CHUNK_STRIDE;
#pragma unroll
    for (int k = 0; k < 3; ++k) {
      int s = w * 3 + k;
      if (s < 11) gl_lds16(srcF[k] + coff, sF[pb] + s * 1024);
    }
#pragma unroll
    for (int k = 0; k < 7; ++k) {
      int s = w + 4 * k;
      if (s < 27)
        gl_lds16(w2g + (size_t)c * W2_CHUNK_B + s * 1024 + lane * 16, sA[pb] + s * 1024);
    }
  };

  stage(0, 0);
  __builtin_amdgcn_s_waitcnt(0);
  __syncthreads();

  for (int c = 0; c < 16; ++c) {
    int pb = c & 1;
    if (c < 15) stage(c + 1, pb ^ 1);
    const char* fA = sA[pb];
    const char* fB = sF[pb];
#pragma unroll
    for (int tp = 0; tp < 9; ++tp) {
      bf16x8 av[3], bv[2];
#pragma unroll
      for (int cf = 0; cf < 3; ++cf)
        av[cf] = *(const bf16x8*)(fA + tp * 3072 + cf * 1024 + aoff);
#pragma unroll
      for (int bf = 0; bf < 2; ++bf)
        bv[bf] = *(const bf16x8*)(fB + idxB[bf] + toff[tp]);
#pragma unroll
      for (int cf = 0; cf < 3; ++cf)
#pragma unroll
        for (int bf = 0; bf < 2; ++bf)
          acc[cf][bf] = __builtin_amdgcn_mfma_f32_16x16x32_bf16(av[cf], bv[bf], acc[cf][bf], 0, 0, 0);
    }
    __builtin_amdgcn_s_waitcnt(0);
    __syncthreads();
  }

  f32x4 bias[3];
#pragma unroll
  for (int cf = 0; cf < 3; ++cf)
    bias[cf] = *(const f32x4*)(beff + cf * 16 + (lane >> 4) * 4);
#pragma unroll
  for (int bf = 0; bf < 2; ++bf) {
    int p = (w * 2 + bf) * 16 + (lane & 15);
    if (p >= mcount) continue;
    int di = p / TJ, dj = p - di * TJ;
    int gm = (b * 50 + i0 + di) * 50 + (j0 + dj);
#pragma unroll
    for (int cf = 0; cf < 3; ++cf) {
      f32x4 v = acc[cf][bf];
#pragma unroll
      for (int r = 0; r < 4; ++r) v[r] += bias[cf][r];
      *(f32x4*)(oh + (size_t)gm * 48 + cf * 16 + (lane >> 4) * 4) = v;
    }
  }
}

// ---------- k4: loss pass + last-block finalize ----------
__global__ __launch_bounds__(256) void k4(const float* __restrict__ gt_boxes,
                                          const unsigned* __restrict__ mxbuf,
                                          const float* __restrict__ oh,
                                          float* __restrict__ accum,
                                          float* __restrict__ dout) {
  int b = blockIdx.y;
  int n = blockIdx.x * 256 + threadIdx.x;
  float s_np = 0.f, s_reg = 0.f, s_pos = 0.f, s_nc = 0.f, s_nl = 0.f;
  if (n < 22500) {
    float ax1, ay1, ax2, ay2;
    anchor_strict(n, ax1, ay1, ax2, ay2);
    float aarea = __fmul_rn(__fsub_rn(ax2, ax1), __fsub_rn(ay2, ay1));
    float acx = (ax1 + ax2) * 0.5f, acy = (ay1 + ay2) * 0.5f;
    float aw = fmaxf(ax2 - ax1, 1e-6f), ah = fmaxf(ay2 - ay1, 1e-6f);
    int ii = n / 450, rem = n - ii * 450, jj = rem / 9, a = rem - jj * 9;
    const float* row = oh + ((size_t)(b * 2500 + ii * 50 + jj)) * 48;
    float logit = row[a];
    float p0 = row[9 + a * 4], p1 = row[10 + a * 4];
    float p2 = row[11 + a * 4], p3 = row[12 + a * 4];
    int npos = 0;
    bool allneg = true;
#pragma unroll
    for (int m = 0; m < 16; ++m) {
      const float* g = gt_boxes + (b * 16 + m) * 4;
      float iou = iou_strict(ax1, ay1, ax2, ay2, aarea, g);
      float mxv = __uint_as_float(mxbuf[b * 16 + m]);
      bool pos = ((iou == mxv) && (mxv > 0.f)) || (iou > 0.7f);
      if (iou >= 0.3f) allneg = false;
      if (pos) {
        ++npos;
        float gx1 = g[0] * 0.0625f, gy1 = g[1] * 0.0625f;
        float gx2 = g[2] * 0.0625f, gy2 = g[3] * 0.0625f;
        float gcx = (gx1 + gx2) * 0.5f, gcy = (gy1 + gy2) * 0.5f;
        float gw = fmaxf(gx2 - gx1, 1e-6f), gh = fmaxf(gy2 - gy1, 1e-6f);
        float tx = (gcx - acx) / aw, ty = (gcy - acy) / ah;
        float twv = logf(gw / aw), thv = logf(gh / ah);
        s_reg += sl1(tx - p0) + sl1(ty - p1) + sl1(twv - p2) + sl1(thv - p3);
      }
    }
    s_np = (float)npos;
    s_pos = (float)npos * softplus_f(-logit);
    if (allneg) { s_nc = 1.f; s_nl = softplus_f(logit); }
    float pcx = acx + p0 * aw, pcy = acy + p1 * ah;
    float pw = aw * expf(p2), ph = ah * expf(p3);
    float* o = dout + 1 + ((size_t)b * 22500 + n) * 4;
    o[0] = pcx - pw * 0.5f;
    o[1] = pcy - ph * 0.5f;
    o[2] = pcx + pw * 0.5f;
    o[3] = pcy + ph * 0.5f;
  }
  float vals[5] = {s_np, s_reg, s_pos, s_nc, s_nl};
  __shared__ float red[4][5];
#pragma unroll
  for (int q = 0; q < 5; ++q) {
    float v = vals[q];
    for (int o = 32; o; o >>= 1) v += __shfl_down(v, o, 64);
    if ((threadIdx.x & 63) == 0) red[threadIdx.x >> 6][q] = v;
  }
  __syncthreads();
  if (threadIdx.x < 5) {
    float v = red[0][threadIdx.x] + red[1][threadIdx.x] +
              red[2][threadIdx.x] + red[3][threadIdx.x];
    atomicAdd(accum + threadIdx.x, v);
  }
  // last-block finalize (replaces k_fin): counter at accum[5], zeroed by k1.
  __syncthreads();                    // drains this block's atomics (vmcnt 0)
  if (threadIdx.x == 0) {
    __threadfence();
    unsigned old = atomicAdd((unsigned*)(accum + 5), 1u);
    if (old == 1407u) {               // 88*16 = 1408 blocks
      float np = fmaxf(atomicAdd(accum + 0, 0.f), 1.f);
      float rg = atomicAdd(accum + 1, 0.f);
      float pp = atomicAdd(accum + 2, 0.f);
      float nn = fmaxf(atomicAdd(accum + 3, 0.f), 1.f);
      float nl = atomicAdd(accum + 4, 0.f);
      dout[0] = 0.5f * (pp / np + nl / nn) + 5.f * (rg / (4.f * np));
    }
  }
}

// ---------- launch ----------
extern "C" void kernel_launch(void* const* d_in, const int* in_sizes, int n_in,
                              void* d_out, int out_size, void* d_ws, size_t ws_size,
                              hipStream_t stream) {
  const float* features = (const float*)d_in[0];
  const float* gt_boxes = (const float*)d_in[1];
  const float* w1    = (const float*)d_in[2];
  const float* b1    = (const float*)d_in[3];
  const float* w_cls = (const float*)d_in[4];
  const float* b_cls = (const float*)d_in[5];
  const float* w_box = (const float*)d_in[6];
  const float* b_box = (const float*)d_in[7];
  float* out = (float*)d_out;
  char* ws = (char*)d_ws;

  // ws layout (featT2 chunk-major: 16*16*2704*64 = 44,302,336 B)
  char*           featT2 = ws;                                  // 44,302,336 B
  unsigned short* w2     = (unsigned short*)(ws + 44302336);    //    442,368 B used
  float*          wpart  = (float*)(ws + 44855296);             //  7,077,888 B
  float*          oh     = (float*)(ws + 51933184);             //  7,680,000 B
  float*          beff   = (float*)(ws + 59613184);             //        192 B
  unsigned*       mx     = (unsigned*)(ws + 59613376);          //      1,024 B
  float*          accum  = (float*)(ws + 59614400);             //         32 B

  k1<<<1536, 256, 0, stream>>>(features, featT2, w1, w_cls, w_box, b1, b_cls,
                               b_box, wpart, beff, mx);
  k2<<<2272, 256, 0, stream>>>(wpart, w2, gt_boxes, mx);
  k3<<<512, 256, 0, stream>>>(featT2, (const char*)w2, beff, oh);
  k4<<<dim3(88, 16), 256, 0, stream>>>(gt_boxes, mx, oh, accum, out);
}

// Round 4
// 251.422 us; speedup vs baseline: 1.0944x; 1.0323x over previous
//
#include <hip/hip_runtime.h>
#include <hip/hip_bf16.h>
#include <stdint.h>

// R13: k1 latency fixes. (a) featT: all 16 float4 loads issued up-front
// (load depth 4 -> 16, ~64 VGPRs of data in flight) instead of 4-load
// batches consumed immediately - R12 showed k1 latency-bound (HBM 24%,
// VALU 11%, occ 26%). (b) weff1: thread = (kmem 64, coq 4) with acc[12]
// (was kmem 256 x all-48-co with acc[48] at VGPR_Count=52 => spill);
// 576 blocks. Same c4-loop & FMA expression per (co,kmem) -> bit-identical
// part. k2/k3/k4 unchanged (awaiting their counters once k1 < top-5).

using bf16x8 = __attribute__((ext_vector_type(8))) __bf16;
using f32x4  = __attribute__((ext_vector_type(4))) float;

// featT2 layout (CHUNK-MAJOR): featT2[chunk 16][img 16][pos 52*52][64 B].
// pos = i*52+j, row/col 0,51 = zero borders. All data bytes written every call
// by the featT role (interior tiles + border tile); no memset.
#define FT_CHUNK_STRIDE 2768896   // 16 img * 2704 pos * 64 B
// W2 layout (PACKED+SWIZZLED): [ci-chunk 16][tap 9][cf 3][rec 16][64 B].
// rec = co&15 within cf block; the 4 ci-quads (16 B each) of record r are
// stored at slot (q ^ (r&3)) so the A-fragment ds_read spreads banks.
#define W2_CHUNK_B 27648

// ---------- helpers ----------
__device__ __forceinline__ unsigned short f2bf(float f) {
  union { float f; unsigned u; } x; x.f = f;
  unsigned r = x.u + 0x7fffu + ((x.u >> 16) & 1u);   // RNE
  return (unsigned short)(r >> 16);
}

__device__ __forceinline__ void gl_lds16(const void* g, void* l) {
  __builtin_amdgcn_global_load_lds(
      (const __attribute__((address_space(1))) void*)g,
      (__attribute__((address_space(3))) void*)l, 16, 0, 0);
}

__device__ __forceinline__ float sl1(float d) {
  float ad = fabsf(d);
  return ad < 1.f ? 0.5f * d * d : ad - 0.5f;
}
__device__ __forceinline__ float softplus_f(float x) {
  return fmaxf(x, 0.f) + log1pf(expf(-fabsf(x)));
}

// strict-fp anchor + IoU: identical bits in the iou-max pass and k_loss (no
// contraction possible through __f*_rn intrinsics) so (iou == max) is exact.
__device__ __forceinline__ void anchor_strict(int n, float& ax1, float& ay1,
                                              float& ax2, float& ay2) {
  int ii = n / 450;
  int rem = n - ii * 450;
  int jj = rem / 9;
  int a  = rem - jj * 9;
  const float SC[3] = {2.f, 4.f, 6.f};
  const float RA[3] = {0.5f, 1.f, 1.5f};
  float w = __fmul_rn(SC[a % 3], RA[a / 3]);
  float h = SC[a % 3];
  float cx = __fadd_rn((float)ii, 0.5f);
  float cy = __fadd_rn((float)jj, 0.5f);
  float wh = __fmul_rn(w, 0.5f), hh = __fmul_rn(h, 0.5f);
  ax1 = fminf(fmaxf(__fsub_rn(cx, wh), 0.f), 50.f);
  ax2 = fminf(fmaxf(__fadd_rn(cx, wh), 0.f), 50.f);
  ay1 = fminf(fmaxf(__fsub_rn(cy, hh), 0.f), 50.f);
  ay2 = fminf(fmaxf(__fadd_rn(cy, hh), 0.f), 50.f);
}
__device__ __forceinline__ float iou_strict(float ax1, float ay1, float ax2, float ay2,
                                            float aarea, const float* __restrict__ g) {
  float gx1 = __fmul_rn(g[0], 0.0625f), gy1 = __fmul_rn(g[1], 0.0625f);
  float gx2 = __fmul_rn(g[2], 0.0625f), gy2 = __fmul_rn(g[3], 0.0625f);
  float ix1 = fmaxf(ax1, gx1), iy1 = fmaxf(ay1, gy1);
  float ix2 = fminf(ax2, gx2), iy2 = fminf(ay2, gy2);
  float inter = __fmul_rn(fmaxf(__fsub_rn(ix2, ix1), 0.f),
                          fmaxf(__fsub_rn(iy2, iy1), 0.f));
  float garea = __fmul_rn(__fsub_rn(gx2, gx1), __fsub_rn(gy2, gy1));
  float denom = __fadd_rn(__fsub_rn(__fadd_rn(aarea, garea), inter), 1e-8f);
  return __fdiv_rn(inter, denom);
}

// ---------- k1: weff1 (blocks 0..575) | bias (576..623) | featT (624..1967)
// weff1: part[cz][co 48][kmem 4608] = sum_{outC in cz} whead[co][outC]*w1[outC][kmem]
// bias:  bias_eff[co] = b_head[co] + whead[co]·b1
// featT: features NCHW fp32 -> chunk-major packed bf16 (LDS transpose).
__global__ __launch_bounds__(256, 4) void k1(const float* __restrict__ feat,
                                             char* __restrict__ featT2,
                                             const float* __restrict__ w1,
                                             const float* __restrict__ wc,
                                             const float* __restrict__ wb,
                                             const float* __restrict__ b1,
                                             const float* __restrict__ bc,
                                             const float* __restrict__ bbx,
                                             float* __restrict__ part,
                                             float* __restrict__ bias_eff,
                                             unsigned* __restrict__ zbuf) {
  __shared__ __align__(16) char smem[128 * 132 * 2];   // featT sT / weff1 sW union
  const int bxr = blockIdx.x;
  const int tid = threadIdx.x;

  if (bxr < 576) {                   // ---- weff1 role: (cz 8) x (kx 72) ----
    if (bxr == 0) {                  // zero mx(256)+accum(8) dwords
      if (tid < 256) zbuf[tid] = 0u;
      if (tid < 8) zbuf[256 + tid] = 0u;
    }
    int cz = bxr / 72, kx = bxr - cz * 72;
    float* sW = (float*)smem;        // [48][64]
#pragma unroll
    for (int q = 0; q < 12; ++q) {
      int idx = tid + q * 256;
      int co = idx >> 6, cl = idx & 63;
      int c = cz * 64 + cl;
      float v = 0.f;
      if (co < 9) v = wc[co * 512 + c];
      else if (co < 45) v = wb[(co - 9) * 512 + c];
      sW[co * 64 + cl] = v;
    }
    __syncthreads();
    const int kmem = kx * 64 + (tid & 63);   // wave = 64 consecutive kmem
    const int coq  = tid >> 6;               // co quarter: co = coq*12 + j
    float acc[12];
#pragma unroll
    for (int j = 0; j < 12; ++j) acc[j] = 0.f;
    const float* w1p = w1 + (size_t)(cz * 64) * 4608 + kmem;
    for (int c4 = 0; c4 < 64; c4 += 4) {
      float f0 = w1p[(size_t)(c4 + 0) * 4608];
      float f1 = w1p[(size_t)(c4 + 1) * 4608];
      float f2 = w1p[(size_t)(c4 + 2) * 4608];
      float f3 = w1p[(size_t)(c4 + 3) * 4608];
#pragma unroll
      for (int j = 0; j < 12; ++j) {
        float4 wv = *(const float4*)&sW[(coq * 12 + j) * 64 + c4];
        acc[j] += wv.x * f0 + wv.y * f1 + wv.z * f2 + wv.w * f3;
      }
    }
    float* dst = part + (size_t)cz * 221184 + kmem;
#pragma unroll
    for (int j = 0; j < 12; ++j) dst[(size_t)(coq * 12 + j) * 4608] = acc[j];
    return;
  }

  if (bxr < 624) {                   // ---- bias-eff role ----
    int co = bxr - 576;
    int l = tid;
    if (l >= 64) return;
    float s = 0.f;
#pragma unroll
    for (int q = 0; q < 8; ++q) {
      int c = q * 64 + l;
      float wv = co < 9 ? wc[co * 512 + c] : (co < 45 ? wb[(co - 9) * 512 + c] : 0.f);
      s += wv * b1[c];
    }
    for (int o = 32; o; o >>= 1) s += __shfl_down(s, o, 64);
    if (l == 0)
      bias_eff[co] = s + (co < 9 ? bc[co] : (co < 45 ? bbx[co - 9] : 0.f));
    return;
  }

  // ---- featT role ----
  const int bxr2 = bxr - 624;             // 0..1343
  const int tile = bxr2 % 21;
  const int rest = bxr2 / 21;
  const int g    = rest & 3;              // ci group: chunks g*4..g*4+3
  const int b    = rest >> 2;
  if (tile == 20) {                       // border: zero 204 positions' chunks
    uint4 z = {0, 0, 0, 0};
    for (int u = tid; u < 204 * 4; u += 256) {
      int p = u & 255; if (p >= 204) p -= 204;     // u%204 without div
      int c4 = u / 204;
      int ip, jp;
      if (p < 52)       { ip = 0;       jp = p; }
      else if (p < 104) { ip = 51;      jp = p - 52; }
      else if (p < 154) { ip = p - 103; jp = 0; }
      else              { ip = p - 153; jp = 51; }
      char* dst = featT2 + (size_t)(g * 4 + c4) * FT_CHUNK_STRIDE
                + (size_t)(b * 2704 + ip * 52 + jp) * 64;
      *(uint4*)(dst)      = z;
      *(uint4*)(dst + 16) = z;
      *(uint4*)(dst + 32) = z;
      *(uint4*)(dst + 48) = z;
    }
    return;
  }
  unsigned short* sT = (unsigned short*)smem;      // [128][132]
  const int pos0 = tile * 128;
  const float* fb = feat + (size_t)b * 1280000 + (size_t)(g * 128) * 2500;
  const int pq = tid & 31;                // pos quad: pos0 + pq*4 .. +3
  const int rg = tid >> 5;                // ci row-group (4 rows), 0..7
  const int p  = pos0 + pq * 4;
  float vv[16][4];                        // [it*4+q][elem] - 64 VGPRs in flight
  if (p + 3 < 2500) {
#pragma unroll
    for (int it = 0; it < 4; ++it)
#pragma unroll
      for (int q = 0; q < 4; ++q) {
        float4 v = *(const float4*)(fb + (size_t)(it * 32 + rg * 4 + q) * 2500 + p);
        vv[it * 4 + q][0] = v.x; vv[it * 4 + q][1] = v.y;
        vv[it * 4 + q][2] = v.z; vv[it * 4 + q][3] = v.w;
      }
  } else {
#pragma unroll
    for (int it = 0; it < 4; ++it)
#pragma unroll
      for (int q = 0; q < 4; ++q)
#pragma unroll
        for (int e = 0; e < 4; ++e)
          vv[it * 4 + q][e] = fb[(size_t)(it * 32 + rg * 4 + q) * 2500 + min(p + e, 2499)];
  }
#pragma unroll
  for (int it = 0; it < 4; ++it) {
    int cb = it * 32 + rg * 4;            // ci within group
#pragma unroll
    for (int pp = 0; pp < 4; ++pp) {
      ushort4 pk;
      pk.x = f2bf(vv[it * 4 + 0][pp]); pk.y = f2bf(vv[it * 4 + 1][pp]);
      pk.z = f2bf(vv[it * 4 + 2][pp]); pk.w = f2bf(vv[it * 4 + 3][pp]);
      *(ushort4*)&sT[(pq * 4 + pp) * 132 + cb] = pk;
    }
  }
  __syncthreads();
#pragma unroll
  for (int q2 = 0; q2 < 2; ++q2) {
    int u = tid + q2 * 256;
    int ch = u >> 7, pr = u & 127;        // consecutive threads -> consecutive pos
    int gp = pos0 + pr;
    if (gp >= 2500) continue;
    int i = gp / 50, j = gp - i * 50;
    char* dst = featT2 + (size_t)(g * 4 + ch) * FT_CHUNK_STRIDE
              + (size_t)(b * 2704 + (i + 1) * 52 + (j + 1)) * 64;
    const uint4* src = (const uint4*)&sT[pr * 132 + ch * 32];
    uint4 a0 = src[0], a1 = src[1], a2 = src[2], a3 = src[3];
    *(uint4*)(dst)      = a0;
    *(uint4*)(dst + 16) = a1;
    *(uint4*)(dst + 32) = a2;
    *(uint4*)(dst + 48) = a3;
  }
}

// ---------- k2: blocks <864: reduce partials -> packed/swizzled W2 (coalesced);
//                blocks >=864: per-(b,gt) max IoU ----------
__global__ __launch_bounds__(256) void k2(const float* __restrict__ part,
                                          unsigned short* __restrict__ w2,
                                          const float* __restrict__ gt_boxes,
                                          unsigned* __restrict__ mx) {
  if (blockIdx.x >= 864) {                   // IoU max pass
    int q = blockIdx.x - 864;                // 0..1407
    int b = q / 88, nb = q - b * 88;
    int n = nb * 256 + threadIdx.x;
    float lm[16];
#pragma unroll
    for (int m = 0; m < 16; ++m) lm[m] = 0.f;
    if (n < 22500) {
      float ax1, ay1, ax2, ay2;
      anchor_strict(n, ax1, ay1, ax2, ay2);
      float aarea = __fmul_rn(__fsub_rn(ax2, ax1), __fsub_rn(ay2, ay1));
#pragma unroll
      for (int m = 0; m < 16; ++m)
        lm[m] = iou_strict(ax1, ay1, ax2, ay2, aarea, gt_boxes + (b * 16 + m) * 4);
    }
    __shared__ float red[4][16];
#pragma unroll
    for (int m = 0; m < 16; ++m) {
      float v = lm[m];
      for (int o = 32; o; o >>= 1) v = fmaxf(v, __shfl_down(v, o, 64));
      if ((threadIdx.x & 63) == 0) red[threadIdx.x >> 6][m] = v;
    }
    __syncthreads();
    if (threadIdx.x < 16) {
      float v = fmaxf(fmaxf(red[0][threadIdx.x], red[1][threadIdx.x]),
                      fmaxf(red[2][threadIdx.x], red[3][threadIdx.x]));
      atomicMax(mx + b * 16 + threadIdx.x, __float_as_uint(v));
    }
    return;
  }
  // W2 reduce, COALESCED: 864 = 48 co * 18 kx; thread -> kmem = kx*256+tid.
  // Wave reads 1 KB contiguous per cz slice (part[cz][co][kmem], kmem-major).
  int co = blockIdx.x / 18, kx = blockIdx.x - co * 18;
  int kmem = kx * 256 + threadIdx.x;       // 0..4607
  const float* p = part + (size_t)co * 4608 + kmem;
  float s = 0.f;
#pragma unroll
  for (int cz = 0; cz < 8; ++cz) s += p[(size_t)cz * 221184];
  int ci = kmem / 9, tap = kmem - ci * 9;
  int c = ci >> 5, e = ci & 31;
  // packed 64-B record, quad q stored at slot q ^ (rec&3)
  int boff = c * W2_CHUNK_B + tap * 3072 + (co >> 4) * 1024 + (co & 15) * 64
           + ((((e >> 3) ^ co) & 3) << 4) + ((e & 7) << 1);
  w2[boff >> 1] = f2bf(s);
}

// ---------- k3: direct conv+head: 4x8 spatial tiles, 2 blocks/CU ----------
__global__ __launch_bounds__(256, 2) void k3(const char* __restrict__ featT2,
                                             const char* __restrict__ w2g,
                                             const float* __restrict__ beff,
                                             float* __restrict__ oh) {
  __shared__ __align__(16) char sF[2][11264];   // <=135 pos * 80 B; 11*1024 staged
  __shared__ __align__(16) char sA[2][27648];   // 9 taps * 3 cf * 16 rec * 64 B
  const int tid = threadIdx.x, lane = tid & 63, w = tid >> 6;
  // XCD-aware swizzle (512 % 8 == 0 -> bijective): XCD x runs images 2x,2x+1.
  const int bx0 = blockIdx.x;
  const int bx = ((bx0 & 7) << 6) | (bx0 >> 3);
  const int b = bx >> 5, tl = bx & 31, tr = tl >> 3, tc = tl & 7;
  const int i0 = tr * 13 - (tr == 3 ? 1 : 0);       // {0,13,26,38}
  const int TI = (tr >= 2) ? 12 : 13;
  const int TJ = (tc < 2) ? 7 : 6;                  // 7+7+6*6 = 50
  const int j0 = (tc < 2) ? tc * 7 : 14 + (tc - 2) * 6;
  const int TJ2 = TJ + 2;
  const int mcount = TI * TJ;                       // <= 91
  const int pieces = (TI + 2) * TJ2 * 5;            // <= 675 16-B pieces/chunk

  // sF staging: piece pi -> (pos, pc); pc==4 is the LDS pad piece (dup of 3).
  const char* srcF[3];
#pragma unroll
  for (int k = 0; k < 3; ++k) {
    int s = w * 3 + k;
    int pi = s * 64 + lane;
    if (pi >= pieces) pi = pieces - 1;
    int pos = pi / 5, pc = pi - pos * 5;
    if (pc > 3) pc = 3;
    int hi = pos / TJ2, hj = pos - hi * TJ2;
    srcF[k] = featT2 + (size_t)(b * 2704 + (i0 + hi) * 52 + (j0 + hj)) * 64 + pc * 16;
  }
  int idxB[2];
#pragma unroll
  for (int bf = 0; bf < 2; ++bf) {
    int p = (w * 2 + bf) * 16 + (lane & 15);
    if (p >= mcount) p = mcount - 1;
    int di = p / TJ, dj = p - di * TJ;
    idxB[bf] = (di * TJ2 + dj) * 80 + (lane >> 4) * 16;
  }
  // A-fragment LDS offset: rec=lane&15, quad slot = (lane>>4) ^ (lane&3)
  const int aoff = (lane & 15) * 64 + ((((lane >> 4) ^ lane) & 3) << 4);
  int toff[9];
#pragma unroll
  for (int tp = 0; tp < 9; ++tp) toff[tp] = ((tp / 3) * TJ2 + (tp % 3)) * 80;

  f32x4 acc[3][2] = {};

  auto stage = [&](int c, int pb) {
    size_t coff = (size_t)c * FT_CHUNK_STRIDE;
#pragma unroll
    for (int k = 0; k < 3; ++k) {
      int s = w * 3 + k;
      if (s < 11) gl_lds16(srcF[k] + coff, sF[pb] + s * 1024);
    }
#pragma unroll
    for (int k = 0; k < 7; ++k) {
      int s = w + 4 * k;
      if (s < 27)
        gl_lds16(w2g + (size_t)c * W2_CHUNK_B + s * 1024 + lane * 16, sA[pb] + s * 1024);
    }
  };

  stage(0, 0);
  __builtin_amdgcn_s_waitcnt(0);
  __syncthreads();

  for (int c = 0; c < 16; ++c) {
    int pb = c & 1;
    if (c < 15) stage(c + 1, pb ^ 1);
    const char* fA = sA[pb];
    const char* fB = sF[pb];
#pragma unroll
    for (int tp = 0; tp < 9; ++tp) {
      bf16x8 av[3], bv[2];
#pragma unroll
      for (int cf = 0; cf < 3; ++cf)
        av[cf] = *(const bf16x8*)(fA + tp * 3072 + cf * 1024 + aoff);
#pragma unroll
      for (int bf = 0; bf < 2; ++bf)
        bv[bf] = *(const bf16x8*)(fB + idxB[bf] + toff[tp]);
#pragma unroll
      for (int cf = 0; cf < 3; ++cf)
#pragma unroll
        for (int bf = 0; bf < 2; ++bf)
          acc[cf][bf] = __builtin_amdgcn_mfma_f32_16x16x32_bf16(av[cf], bv[bf], acc[cf][bf], 0, 0, 0);
    }
    __builtin_amdgcn_s_waitcnt(0);
    __syncthreads();
  }

  f32x4 bias[3];
#pragma unroll
  for (int cf = 0; cf < 3; ++cf)
    bias[cf] = *(const f32x4*)(beff + cf * 16 + (lane >> 4) * 4);
#pragma unroll
  for (int bf = 0; bf < 2; ++bf) {
    int p = (w * 2 + bf) * 16 + (lane & 15);
    if (p >= mcount) continue;
    int di = p / TJ, dj = p - di * TJ;
    int gm = (b * 50 + i0 + di) * 50 + (j0 + dj);
#pragma unroll
    for (int cf = 0; cf < 3; ++cf) {
      f32x4 v = acc[cf][bf];
#pragma unroll
      for (int r = 0; r < 4; ++r) v[r] += bias[cf][r];
      *(f32x4*)(oh + (size_t)gm * 48 + cf * 16 + (lane >> 4) * 4) = v;
    }
  }
}

// ---------- k4: loss pass + last-block finalize ----------
__global__ __launch_bounds__(256) void k4(const float* __restrict__ gt_boxes,
                                          const unsigned* __restrict__ mxbuf,
                                          const float* __restrict__ oh,
                                          float* __restrict__ accum,
                                          float* __restrict__ dout) {
  int b = blockIdx.y;
  int n = blockIdx.x * 256 + threadIdx.x;
  float s_np = 0.f, s_reg = 0.f, s_pos = 0.f, s_nc = 0.f, s_nl = 0.f;
  if (n < 22500) {
    float ax1, ay1, ax2, ay2;
    anchor_strict(n, ax1, ay1, ax2, ay2);
    float aarea = __fmul_rn(__fsub_rn(ax2, ax1), __fsub_rn(ay2, ay1));
    float acx = (ax1 + ax2) * 0.5f, acy = (ay1 + ay2) * 0.5f;
    float aw = fmaxf(ax2 - ax1, 1e-6f), ah = fmaxf(ay2 - ay1, 1e-6f);
    int ii = n / 450, rem = n - ii * 450, jj = rem / 9, a = rem - jj * 9;
    const float* row = oh + ((size_t)(b * 2500 + ii * 50 + jj)) * 48;
    float logit = row[a];
    float p0 = row[9 + a * 4], p1 = row[10 + a * 4];
    float p2 = row[11 + a * 4], p3 = row[12 + a * 4];
    int npos = 0;
    bool allneg = true;
#pragma unroll
    for (int m = 0; m < 16; ++m) {
      const float* g = gt_boxes + (b * 16 + m) * 4;
      float iou = iou_strict(ax1, ay1, ax2, ay2, aarea, g);
      float mxv = __uint_as_float(mxbuf[b * 16 + m]);
      bool pos = ((iou == mxv) && (mxv > 0.f)) || (iou > 0.7f);
      if (iou >= 0.3f) allneg = false;
      if (pos) {
        ++npos;
        float gx1 = g[0] * 0.0625f, gy1 = g[1] * 0.0625f;
        float gx2 = g[2] * 0.0625f, gy2 = g[3] * 0.0625f;
        float gcx = (gx1 + gx2) * 0.5f, gcy = (gy1 + gy2) * 0.5f;
        float gw = fmaxf(gx2 - gx1, 1e-6f), gh = fmaxf(gy2 - gy1, 1e-6f);
        float tx = (gcx - acx) / aw, ty = (gcy - acy) / ah;
        float twv = logf(gw / aw), thv = logf(gh / ah);
        s_reg += sl1(tx - p0) + sl1(ty - p1) + sl1(twv - p2) + sl1(thv - p3);
      }
    }
    s_np = (float)npos;
    s_pos = (float)npos * softplus_f(-logit);
    if (allneg) { s_nc = 1.f; s_nl = softplus_f(logit); }
    float pcx = acx + p0 * aw, pcy = acy + p1 * ah;
    float pw = aw * expf(p2), ph = ah * expf(p3);
    float* o = dout + 1 + ((size_t)b * 22500 + n) * 4;
    o[0] = pcx - pw * 0.5f;
    o[1] = pcy - ph * 0.5f;
    o[2] = pcx + pw * 0.5f;
    o[3] = pcy + ph * 0.5f;
  }
  float vals[5] = {s_np, s_reg, s_pos, s_nc, s_nl};
  __shared__ float red[4][5];
#pragma unroll
  for (int q = 0; q < 5; ++q) {
    float v = vals[q];
    for (int o = 32; o; o >>= 1) v += __shfl_down(v, o, 64);
    if ((threadIdx.x & 63) == 0) red[threadIdx.x >> 6][q] = v;
  }
  __syncthreads();
  if (threadIdx.x < 5) {
    float v = red[0][threadIdx.x] + red[1][threadIdx.x] +
              red[2][threadIdx.x] + red[3][threadIdx.x];
    atomicAdd(accum + threadIdx.x, v);
  }
  // last-block finalize (replaces k_fin): counter at accum[5], zeroed by k1.
  __syncthreads();                    // drains this block's atomics (vmcnt 0)
  if (threadIdx.x == 0) {
    __threadfence();
    unsigned old = atomicAdd((unsigned*)(accum + 5), 1u);
    if (old == 1407u) {               // 88*16 = 1408 blocks
      float np = fmaxf(atomicAdd(accum + 0, 0.f), 1.f);
      float rg = atomicAdd(accum + 1, 0.f);
      float pp = atomicAdd(accum + 2, 0.f);
      float nn = fmaxf(atomicAdd(accum + 3, 0.f), 1.f);
      float nl = atomicAdd(accum + 4, 0.f);
      dout[0] = 0.5f * (pp / np + nl / nn) + 5.f * (rg / (4.f * np));
    }
  }
}

// ---------- launch ----------
extern "C" void kernel_launch(void* const* d_in, const int* in_sizes, int n_in,
                              void* d_out, int out_size, void* d_ws, size_t ws_size,
                              hipStream_t stream) {
  const float* features = (const float*)d_in[0];
  const float* gt_boxes = (const float*)d_in[1];
  const float* w1    = (const float*)d_in[2];
  const float* b1    = (const float*)d_in[3];
  const float* w_cls = (const float*)d_in[4];
  const float* b_cls = (const float*)d_in[5];
  const float* w_box = (const float*)d_in[6];
  const float* b_box = (const float*)d_in[7];
  float* out = (float*)d_out;
  char* ws = (char*)d_ws;

  // ws layout (featT2 chunk-major: 16*16*2704*64 = 44,302,336 B)
  char*           featT2 = ws;                                  // 44,302,336 B
  unsigned short* w2     = (unsigned short*)(ws + 44302336);    //    442,368 B used
  float*          wpart  = (float*)(ws + 44855296);             //  7,077,888 B
  float*          oh     = (float*)(ws + 51933184);             //  7,680,000 B
  float*          beff   = (float*)(ws + 59613184);             //        192 B
  unsigned*       mx     = (unsigned*)(ws + 59613376);          //      1,024 B
  float*          accum  = (float*)(ws + 59614400);             //         32 B

  k1<<<1968, 256, 0, stream>>>(features, featT2, w1, w_cls, w_box, b1, b_cls,
                               b_box, wpart, beff, mx);
  k2<<<2272, 256, 0, stream>>>(wpart, w2, gt_boxes, mx);
  k3<<<512, 256, 0, stream>>>(featT2, (const char*)w2, beff, oh);
  k4<<<dim3(88, 16), 256, 0, stream>>>(gt_boxes, mx, oh, accum, out);
}

// Round 5
// 238.116 us; speedup vs baseline: 1.1556x; 1.0559x over previous
//
#include <hip/hip_runtime.h>
#include <hip/hip_bf16.h>
#include <stdint.h>

// R14: latency/occupancy attack on k1+k4 (R13 counters: k1 50.8us VGPR=56,
// k4 49.9us VGPR=24 - both all-pipes-idle latency-bound).
// (a) featT tile 128->64 pos: LDS 33.8->16.9 KB => 8 blocks/CU (32 waves, was
//     16) - hide HBM latency via TLP since compiler defeats ILP (sinks loads).
// (b) IoU-max: moved k2->k1 as 256-block role (one block per (b,gt), plain
//     store, max is order-independent; no atomics, no pre-zero of mx).
// (c) k4: 2 anchors/thread in ONE interleaved m-loop + per-gt constants
//     precomputed in LDS (same fp op sequence -> iou==mx still bit-exact).
// k2 = W2-reduce only (864 blocks). k3 unchanged.

using bf16x8 = __attribute__((ext_vector_type(8))) __bf16;
using f32x4  = __attribute__((ext_vector_type(4))) float;

// featT2 layout (CHUNK-MAJOR): featT2[chunk 16][img 16][pos 52*52][64 B].
#define FT_CHUNK_STRIDE 2768896   // 16 img * 2704 pos * 64 B
// W2 layout (PACKED+SWIZZLED): [ci-chunk 16][tap 9][cf 3][rec 16][64 B].
#define W2_CHUNK_B 27648

// ---------- helpers ----------
__device__ __forceinline__ unsigned short f2bf(float f) {
  union { float f; unsigned u; } x; x.f = f;
  unsigned r = x.u + 0x7fffu + ((x.u >> 16) & 1u);   // RNE
  return (unsigned short)(r >> 16);
}

__device__ __forceinline__ void gl_lds16(const void* g, void* l) {
  __builtin_amdgcn_global_load_lds(
      (const __attribute__((address_space(1))) void*)g,
      (__attribute__((address_space(3))) void*)l, 16, 0, 0);
}

__device__ __forceinline__ float sl1(float d) {
  float ad = fabsf(d);
  return ad < 1.f ? 0.5f * d * d : ad - 0.5f;
}
__device__ __forceinline__ float softplus_f(float x) {
  return fmaxf(x, 0.f) + log1pf(expf(-fabsf(x)));
}

// strict-fp anchor + IoU: identical bit sequences in the k1 iou-max role and
// k4 (no contraction through __f*_rn) so the (iou == max) test is exact.
__device__ __forceinline__ void anchor_strict(int n, float& ax1, float& ay1,
                                              float& ax2, float& ay2) {
  int ii = n / 450;
  int rem = n - ii * 450;
  int jj = rem / 9;
  int a  = rem - jj * 9;
  const float SC[3] = {2.f, 4.f, 6.f};
  const float RA[3] = {0.5f, 1.f, 1.5f};
  float w = __fmul_rn(SC[a % 3], RA[a / 3]);
  float h = SC[a % 3];
  float cx = __fadd_rn((float)ii, 0.5f);
  float cy = __fadd_rn((float)jj, 0.5f);
  float wh = __fmul_rn(w, 0.5f), hh = __fmul_rn(h, 0.5f);
  ax1 = fminf(fmaxf(__fsub_rn(cx, wh), 0.f), 50.f);
  ax2 = fminf(fmaxf(__fadd_rn(cx, wh), 0.f), 50.f);
  ay1 = fminf(fmaxf(__fsub_rn(cy, hh), 0.f), 50.f);
  ay2 = fminf(fmaxf(__fadd_rn(cy, hh), 0.f), 50.f);
}
// s = {gx1,gy1,gx2,gy2,garea} precomputed with the exact ops iou_strict used.
__device__ __forceinline__ float iou_pre(float ax1, float ay1, float ax2, float ay2,
                                         float aarea, const float* __restrict__ s) {
  float ix1 = fmaxf(ax1, s[0]), iy1 = fmaxf(ay1, s[1]);
  float ix2 = fminf(ax2, s[2]), iy2 = fminf(ay2, s[3]);
  float inter = __fmul_rn(fmaxf(__fsub_rn(ix2, ix1), 0.f),
                          fmaxf(__fsub_rn(iy2, iy1), 0.f));
  float denom = __fadd_rn(__fsub_rn(__fadd_rn(aarea, s[4]), inter), 1e-8f);
  return __fdiv_rn(inter, denom);
}
__device__ __forceinline__ float iou_strict(float ax1, float ay1, float ax2, float ay2,
                                            float aarea, const float* __restrict__ g) {
  float s[5];
  s[0] = __fmul_rn(g[0], 0.0625f); s[1] = __fmul_rn(g[1], 0.0625f);
  s[2] = __fmul_rn(g[2], 0.0625f); s[3] = __fmul_rn(g[3], 0.0625f);
  s[4] = __fmul_rn(__fsub_rn(s[2], s[0]), __fsub_rn(s[3], s[1]));
  return iou_pre(ax1, ay1, ax2, ay2, aarea, s);
}

// ---------- k1: weff1 (0..575) | bias (576..623) | iou-max (624..879) |
//                featT (880..3503)
__global__ __launch_bounds__(256, 4) void k1(const float* __restrict__ feat,
                                             char* __restrict__ featT2,
                                             const float* __restrict__ w1,
                                             const float* __restrict__ wc,
                                             const float* __restrict__ wb,
                                             const float* __restrict__ b1,
                                             const float* __restrict__ bc,
                                             const float* __restrict__ bbx,
                                             float* __restrict__ part,
                                             float* __restrict__ bias_eff,
                                             const float* __restrict__ gt_boxes,
                                             unsigned* __restrict__ mx,
                                             unsigned* __restrict__ accz) {
  __shared__ __align__(16) char smem[64 * 132 * 2];   // 16896 B union
  const int bxr = blockIdx.x;
  const int tid = threadIdx.x;

  if (bxr < 576) {                   // ---- weff1 role: (cz 8) x (kx 72) ----
    if (bxr == 0 && tid < 8) accz[tid] = 0u;   // zero accum(6 used)+spare
    int cz = bxr / 72, kx = bxr - cz * 72;
    float* sW = (float*)smem;        // [48][64] = 12288 B
#pragma unroll
    for (int q = 0; q < 12; ++q) {
      int idx = tid + q * 256;
      int co = idx >> 6, cl = idx & 63;
      int c = cz * 64 + cl;
      float v = 0.f;
      if (co < 9) v = wc[co * 512 + c];
      else if (co < 45) v = wb[(co - 9) * 512 + c];
      sW[co * 64 + cl] = v;
    }
    __syncthreads();
    const int kmem = kx * 64 + (tid & 63);   // wave = 64 consecutive kmem
    const int coq  = tid >> 6;               // co quarter: co = coq*12 + j
    float acc[12];
#pragma unroll
    for (int j = 0; j < 12; ++j) acc[j] = 0.f;
    const float* w1p = w1 + (size_t)(cz * 64) * 4608 + kmem;
    for (int c4 = 0; c4 < 64; c4 += 4) {
      float f0 = w1p[(size_t)(c4 + 0) * 4608];
      float f1 = w1p[(size_t)(c4 + 1) * 4608];
      float f2 = w1p[(size_t)(c4 + 2) * 4608];
      float f3 = w1p[(size_t)(c4 + 3) * 4608];
#pragma unroll
      for (int j = 0; j < 12; ++j) {
        float4 wv = *(const float4*)&sW[(coq * 12 + j) * 64 + c4];
        acc[j] += wv.x * f0 + wv.y * f1 + wv.z * f2 + wv.w * f3;
      }
    }
    float* dst = part + (size_t)cz * 221184 + kmem;
#pragma unroll
    for (int j = 0; j < 12; ++j) dst[(size_t)(coq * 12 + j) * 4608] = acc[j];
    return;
  }

  if (bxr < 624) {                   // ---- bias-eff role ----
    int co = bxr - 576;
    int l = tid;
    if (l >= 64) return;
    float s = 0.f;
#pragma unroll
    for (int q = 0; q < 8; ++q) {
      int c = q * 64 + l;
      float wv = co < 9 ? wc[co * 512 + c] : (co < 45 ? wb[(co - 9) * 512 + c] : 0.f);
      s += wv * b1[c];
    }
    for (int o = 32; o; o >>= 1) s += __shfl_down(s, o, 64);
    if (l == 0)
      bias_eff[co] = s + (co < 9 ? bc[co] : (co < 45 ? bbx[co - 9] : 0.f));
    return;
  }

  if (bxr < 880) {                   // ---- iou-max role: one block per (b,m) ----
    int q = bxr - 624;               // 0..255
    int b = q >> 4, m = q & 15;
    const float* g = gt_boxes + (b * 16 + m) * 4;
    float s[5];
    s[0] = __fmul_rn(g[0], 0.0625f); s[1] = __fmul_rn(g[1], 0.0625f);
    s[2] = __fmul_rn(g[2], 0.0625f); s[3] = __fmul_rn(g[3], 0.0625f);
    s[4] = __fmul_rn(__fsub_rn(s[2], s[0]), __fsub_rn(s[3], s[1]));
    float best = 0.f;
    for (int n = tid; n < 22500; n += 256) {
      float ax1, ay1, ax2, ay2;
      anchor_strict(n, ax1, ay1, ax2, ay2);
      float aarea = __fmul_rn(__fsub_rn(ax2, ax1), __fsub_rn(ay2, ay1));
      best = fmaxf(best, iou_pre(ax1, ay1, ax2, ay2, aarea, s));
    }
    for (int o = 32; o; o >>= 1) best = fmaxf(best, __shfl_down(best, o, 64));
    float* red = (float*)smem;
    if ((tid & 63) == 0) red[tid >> 6] = best;
    __syncthreads();
    if (tid == 0) {
      float v = fmaxf(fmaxf(red[0], red[1]), fmaxf(red[2], red[3]));
      mx[b * 16 + m] = __float_as_uint(v);
    }
    return;
  }

  // ---- featT role: 64-pos tiles ----
  const int bxr2 = bxr - 880;             // 0..2623
  const int tile = bxr2 % 41;
  const int rest = bxr2 / 41;
  const int g    = rest & 3;              // ci group: chunks g*4..g*4+3
  const int b    = rest >> 2;
  if (tile == 40) {                       // border: zero 204 positions' chunks
    uint4 z = {0, 0, 0, 0};
    for (int u = tid; u < 204 * 4; u += 256) {
      int p = u & 255; if (p >= 204) p -= 204;     // u%204 without div
      int c4 = u / 204;
      int ip, jp;
      if (p < 52)       { ip = 0;       jp = p; }
      else if (p < 104) { ip = 51;      jp = p - 52; }
      else if (p < 154) { ip = p - 103; jp = 0; }
      else              { ip = p - 153; jp = 51; }
      char* dst = featT2 + (size_t)(g * 4 + c4) * FT_CHUNK_STRIDE
                + (size_t)(b * 2704 + ip * 52 + jp) * 64;
      *(uint4*)(dst)      = z;
      *(uint4*)(dst + 16) = z;
      *(uint4*)(dst + 32) = z;
      *(uint4*)(dst + 48) = z;
    }
    return;
  }
  unsigned short* sT = (unsigned short*)smem;      // [64 pos][132 ci]
  const int pos0 = tile * 64;
  const float* fb = feat + (size_t)b * 1280000 + (size_t)(g * 128) * 2500;
  const int pq = tid & 15;                // pos quad: pos0 + pq*4 .. +3
  const int cq = tid >> 4;                // ci quad group 0..15
  const int p  = pos0 + pq * 4;
  float vv[2][4][4];                      // [it][q][elem]
  if (p + 3 < 2500) {
#pragma unroll
    for (int it = 0; it < 2; ++it)
#pragma unroll
      for (int q = 0; q < 4; ++q) {
        float4 v = *(const float4*)(fb + (size_t)(it * 64 + cq * 4 + q) * 2500 + p);
        vv[it][q][0] = v.x; vv[it][q][1] = v.y;
        vv[it][q][2] = v.z; vv[it][q][3] = v.w;
      }
  } else {
#pragma unroll
    for (int it = 0; it < 2; ++it)
#pragma unroll
      for (int q = 0; q < 4; ++q)
#pragma unroll
        for (int e = 0; e < 4; ++e)
          vv[it][q][e] = fb[(size_t)(it * 64 + cq * 4 + q) * 2500 + min(p + e, 2499)];
  }
#pragma unroll
  for (int it = 0; it < 2; ++it) {
#pragma unroll
    for (int pp = 0; pp < 4; ++pp) {
      ushort4 pk;
      pk.x = f2bf(vv[it][0][pp]); pk.y = f2bf(vv[it][1][pp]);
      pk.z = f2bf(vv[it][2][pp]); pk.w = f2bf(vv[it][3][pp]);
      *(ushort4*)&sT[(pq * 4 + pp) * 132 + it * 64 + cq * 4] = pk;
    }
  }
  __syncthreads();
  {
    int ch = tid >> 6, pr = tid & 63;     // consecutive threads -> consecutive pos
    int gp = pos0 + pr;
    if (gp < 2500) {
      int i = gp / 50, j = gp - i * 50;
      char* dst = featT2 + (size_t)(g * 4 + ch) * FT_CHUNK_STRIDE
                + (size_t)(b * 2704 + (i + 1) * 52 + (j + 1)) * 64;
      const uint4* src = (const uint4*)&sT[pr * 132 + ch * 32];
      uint4 a0 = src[0], a1 = src[1], a2 = src[2], a3 = src[3];
      *(uint4*)(dst)      = a0;
      *(uint4*)(dst + 16) = a1;
      *(uint4*)(dst + 32) = a2;
      *(uint4*)(dst + 48) = a3;
    }
  }
}

// ---------- k2: reduce partials -> packed/swizzled W2 (coalesced) ----------
__global__ __launch_bounds__(256) void k2(const float* __restrict__ part,
                                          unsigned short* __restrict__ w2) {
  // 864 = 48 co * 18 kx; thread -> kmem = kx*256+tid.
  int co = blockIdx.x / 18, kx = blockIdx.x - co * 18;
  int kmem = kx * 256 + threadIdx.x;       // 0..4607
  const float* p = part + (size_t)co * 4608 + kmem;
  float s = 0.f;
#pragma unroll
  for (int cz = 0; cz < 8; ++cz) s += p[(size_t)cz * 221184];
  int ci = kmem / 9, tap = kmem - ci * 9;
  int c = ci >> 5, e = ci & 31;
  // packed 64-B record, quad q stored at slot q ^ (rec&3)
  int boff = c * W2_CHUNK_B + tap * 3072 + (co >> 4) * 1024 + (co & 15) * 64
           + ((((e >> 3) ^ co) & 3) << 4) + ((e & 7) << 1);
  w2[boff >> 1] = f2bf(s);
}

// ---------- k3: direct conv+head: 4x8 spatial tiles, 2 blocks/CU ----------
__global__ __launch_bounds__(256, 2) void k3(const char* __restrict__ featT2,
                                             const char* __restrict__ w2g,
                                             const float* __restrict__ beff,
                                             float* __restrict__ oh) {
  __shared__ __align__(16) char sF[2][11264];   // <=135 pos * 80 B; 11*1024 staged
  __shared__ __align__(16) char sA[2][27648];   // 9 taps * 3 cf * 16 rec * 64 B
  const int tid = threadIdx.x, lane = tid & 63, w = tid >> 6;
  // XCD-aware swizzle (512 % 8 == 0 -> bijective): XCD x runs images 2x,2x+1.
  const int bx0 = blockIdx.x;
  const int bx = ((bx0 & 7) << 6) | (bx0 >> 3);
  const int b = bx >> 5, tl = bx & 31, tr = tl >> 3, tc = tl & 7;
  const int i0 = tr * 13 - (tr == 3 ? 1 : 0);       // {0,13,26,38}
  const int TI = (tr >= 2) ? 12 : 13;
  const int TJ = (tc < 2) ? 7 : 6;                  // 7+7+6*6 = 50
  const int j0 = (tc < 2) ? tc * 7 : 14 + (tc - 2) * 6;
  const int TJ2 = TJ + 2;
  const int mcount = TI * TJ;                       // <= 91
  const int pieces = (TI + 2) * TJ2 * 5;            // <= 675 16-B pieces/chunk

  const char* srcF[3];
#pragma unroll
  for (int k = 0; k < 3; ++k) {
    int s = w * 3 + k;
    int pi = s * 64 + lane;
    if (pi >= pieces) pi = pieces - 1;
    int pos = pi / 5, pc = pi - pos * 5;
    if (pc > 3) pc = 3;
    int hi = pos / TJ2, hj = pos - hi * TJ2;
    srcF[k] = featT2 + (size_t)(b * 2704 + (i0 + hi) * 52 + (j0 + hj)) * 64 + pc * 16;
  }
  int idxB[2];
#pragma unroll
  for (int bf = 0; bf < 2; ++bf) {
    int p = (w * 2 + bf) * 16 + (lane & 15);
    if (p >= mcount) p = mcount - 1;
    int di = p / TJ, dj = p - di * TJ;
    idxB[bf] = (di * TJ2 + dj) * 80 + (lane >> 4) * 16;
  }
  // A-fragment LDS offset: rec=lane&15, quad slot = (lane>>4) ^ (lane&3)
  const int aoff = (lane & 15) * 64 + ((((lane >> 4) ^ lane) & 3) << 4);
  int toff[9];
#pragma unroll
  for (int tp = 0; tp < 9; ++tp) toff[tp] = ((tp / 3) * TJ2 + (tp % 3)) * 80;

  f32x4 acc[3][2] = {};

  auto stage = [&](int c, int pb) {
    size_t coff = (size_t)c * FT_CHUNK_STRIDE;
#pragma unroll
    for (int k = 0; k < 3; ++k) {
      int s = w * 3 + k;
      if (s < 11) gl_lds16(srcF[k] + coff, sF[pb] + s * 1024);
    }
#pragma unroll
    for (int k = 0; k < 7; ++k) {
      int s = w + 4 * k;
      if (s < 27)
        gl_lds16(w2g + (size_t)c * W2_CHUNK_B + s * 1024 + lane * 16, sA[pb] + s * 1024);
    }
  };

  stage(0, 0);
  __builtin_amdgcn_s_waitcnt(0);
  __syncthreads();

  for (int c = 0; c < 16; ++c) {
    int pb = c & 1;
    if (c < 15) stage(c + 1, pb ^ 1);
    const char* fA = sA[pb];
    const char* fB = sF[pb];
#pragma unroll
    for (int tp = 0; tp < 9; ++tp) {
      bf16x8 av[3], bv[2];
#pragma unroll
      for (int cf = 0; cf < 3; ++cf)
        av[cf] = *(const bf16x8*)(fA + tp * 3072 + cf * 1024 + aoff);
#pragma unroll
      for (int bf = 0; bf < 2; ++bf)
        bv[bf] = *(const bf16x8*)(fB + idxB[bf] + toff[tp]);
#pragma unroll
      for (int cf = 0; cf < 3; ++cf)
#pragma unroll
        for (int bf = 0; bf < 2; ++bf)
          acc[cf][bf] = __builtin_amdgcn_mfma_f32_16x16x32_bf16(av[cf], bv[bf], acc[cf][bf], 0, 0, 0);
    }
    __builtin_amdgcn_s_waitcnt(0);
    __syncthreads();
  }

  f32x4 bias[3];
#pragma unroll
  for (int cf = 0; cf < 3; ++cf)
    bias[cf] = *(const f32x4*)(beff + cf * 16 + (lane >> 4) * 4);
#pragma unroll
  for (int bf = 0; bf < 2; ++bf) {
    int p = (w * 2 + bf) * 16 + (lane & 15);
    if (p >= mcount) continue;
    int di = p / TJ, dj = p - di * TJ;
    int gm = (b * 50 + i0 + di) * 50 + (j0 + dj);
#pragma unroll
    for (int cf = 0; cf < 3; ++cf) {
      f32x4 v = acc[cf][bf];
#pragma unroll
      for (int r = 0; r < 4; ++r) v[r] += bias[cf][r];
      *(f32x4*)(oh + (size_t)gm * 48 + cf * 16 + (lane >> 4) * 4) = v;
    }
  }
}

// ---------- k4: loss pass (2 anchors/thread) + last-block finalize ----------
__global__ __launch_bounds__(256) void k4(const float* __restrict__ gt_boxes,
                                          const unsigned* __restrict__ mxbuf,
                                          const float* __restrict__ oh,
                                          float* __restrict__ accum,
                                          float* __restrict__ dout) {
  const int tid = threadIdx.x;
  const int b = blockIdx.y;
  __shared__ float sg[16][10];   // gx1,gy1,gx2,gy2,garea,gcx,gcy,gw,gh
  if (tid < 16) {
    const float* g = gt_boxes + (b * 16 + tid) * 4;
    float gx1 = __fmul_rn(g[0], 0.0625f), gy1 = __fmul_rn(g[1], 0.0625f);
    float gx2 = __fmul_rn(g[2], 0.0625f), gy2 = __fmul_rn(g[3], 0.0625f);
    sg[tid][0] = gx1; sg[tid][1] = gy1; sg[tid][2] = gx2; sg[tid][3] = gy2;
    sg[tid][4] = __fmul_rn(__fsub_rn(gx2, gx1), __fsub_rn(gy2, gy1));
    sg[tid][5] = (gx1 + gx2) * 0.5f;
    sg[tid][6] = (gy1 + gy2) * 0.5f;
    sg[tid][7] = fmaxf(gx2 - gx1, 1e-6f);
    sg[tid][8] = fmaxf(gy2 - gy1, 1e-6f);
  }
  __syncthreads();

  const int n0 = blockIdx.x * 512 + tid;
  const int n1 = n0 + 256;
  const bool vA = n0 < 22500, vB = n1 < 22500;
  float s_np = 0.f, s_reg = 0.f, s_pos = 0.f, s_nc = 0.f, s_nl = 0.f;

  float Aax1 = 0, Aay1 = 0, Aax2 = 0, Aay2 = 0, Aarea = 0, Aacx = 0, Aacy = 0,
        Aaw = 1, Aah = 1, Alog = 0, Ap0 = 0, Ap1 = 0, Ap2 = 0, Ap3 = 0;
  float Bax1 = 0, Bay1 = 0, Bax2 = 0, Bay2 = 0, Barea = 0, Bacx = 0, Bacy = 0,
        Baw = 1, Bah = 1, Blog = 0, Bp0 = 0, Bp1 = 0, Bp2 = 0, Bp3 = 0;
  int npA = 0, npB = 0;
  bool anA = true, anB = true;

  if (vA) {
    anchor_strict(n0, Aax1, Aay1, Aax2, Aay2);
    Aarea = __fmul_rn(__fsub_rn(Aax2, Aax1), __fsub_rn(Aay2, Aay1));
    Aacx = (Aax1 + Aax2) * 0.5f; Aacy = (Aay1 + Aay2) * 0.5f;
    Aaw = fmaxf(Aax2 - Aax1, 1e-6f); Aah = fmaxf(Aay2 - Aay1, 1e-6f);
    int ii = n0 / 450, rem = n0 - ii * 450, jj = rem / 9, a = rem - jj * 9;
    const float* row = oh + ((size_t)(b * 2500 + ii * 50 + jj)) * 48;
    Alog = row[a];
    Ap0 = row[9 + a * 4]; Ap1 = row[10 + a * 4];
    Ap2 = row[11 + a * 4]; Ap3 = row[12 + a * 4];
  }
  if (vB) {
    anchor_strict(n1, Bax1, Bay1, Bax2, Bay2);
    Barea = __fmul_rn(__fsub_rn(Bax2, Bax1), __fsub_rn(Bay2, Bay1));
    Bacx = (Bax1 + Bax2) * 0.5f; Bacy = (Bay1 + Bay2) * 0.5f;
    Baw = fmaxf(Bax2 - Bax1, 1e-6f); Bah = fmaxf(Bay2 - Bay1, 1e-6f);
    int ii = n1 / 450, rem = n1 - ii * 450, jj = rem / 9, a = rem - jj * 9;
    const float* row = oh + ((size_t)(b * 2500 + ii * 50 + jj)) * 48;
    Blog = row[a];
    Bp0 = row[9 + a * 4]; Bp1 = row[10 + a * 4];
    Bp2 = row[11 + a * 4]; Bp3 = row[12 + a * 4];
  }

#pragma unroll
  for (int m = 0; m < 16; ++m) {
    const float* s = sg[m];
    float mxv = __uint_as_float(mxbuf[b * 16 + m]);
    float iouA = vA ? iou_pre(Aax1, Aay1, Aax2, Aay2, Aarea, s) : 0.f;
    float iouB = vB ? iou_pre(Bax1, Bay1, Bax2, Bay2, Barea, s) : 0.f;
    if (vA) {
      bool pos = ((iouA == mxv) && (mxv > 0.f)) || (iouA > 0.7f);
      if (iouA >= 0.3f) anA = false;
      if (pos) {
        ++npA;
        float tx = (s[5] - Aacx) / Aaw, ty = (s[6] - Aacy) / Aah;
        float twv = logf(s[7] / Aaw), thv = logf(s[8] / Aah);
        s_reg += sl1(tx - Ap0) + sl1(ty - Ap1) + sl1(twv - Ap2) + sl1(thv - Ap3);
      }
    }
    if (vB) {
      bool pos = ((iouB == mxv) && (mxv > 0.f)) || (iouB > 0.7f);
      if (iouB >= 0.3f) anB = false;
      if (pos) {
        ++npB;
        float tx = (s[5] - Bacx) / Baw, ty = (s[6] - Bacy) / Bah;
        float twv = logf(s[7] / Baw), thv = logf(s[8] / Bah);
        s_reg += sl1(tx - Bp0) + sl1(ty - Bp1) + sl1(twv - Bp2) + sl1(thv - Bp3);
      }
    }
  }
  if (vA) {
    s_np += (float)npA;
    s_pos += (float)npA * softplus_f(-Alog);
    if (anA) { s_nc += 1.f; s_nl += softplus_f(Alog); }
    float pcx = Aacx + Ap0 * Aaw, pcy = Aacy + Ap1 * Aah;
    float pw = Aaw * expf(Ap2), ph = Aah * expf(Ap3);
    float* o = dout + 1 + ((size_t)b * 22500 + n0) * 4;
    o[0] = pcx - pw * 0.5f; o[1] = pcy - ph * 0.5f;
    o[2] = pcx + pw * 0.5f; o[3] = pcy + ph * 0.5f;
  }
  if (vB) {
    s_np += (float)npB;
    s_pos += (float)npB * softplus_f(-Blog);
    if (anB) { s_nc += 1.f; s_nl += softplus_f(Blog); }
    float pcx = Bacx + Bp0 * Baw, pcy = Bacy + Bp1 * Bah;
    float pw = Baw * expf(Bp2), ph = Bah * expf(Bp3);
    float* o = dout + 1 + ((size_t)b * 22500 + n1) * 4;
    o[0] = pcx - pw * 0.5f; o[1] = pcy - ph * 0.5f;
    o[2] = pcx + pw * 0.5f; o[3] = pcy + ph * 0.5f;
  }

  float vals[5] = {s_np, s_reg, s_pos, s_nc, s_nl};
  __shared__ float red[4][5];
#pragma unroll
  for (int q = 0; q < 5; ++q) {
    float v = vals[q];
    for (int o = 32; o; o >>= 1) v += __shfl_down(v, o, 64);
    if ((tid & 63) == 0) red[tid >> 6][q] = v;
  }
  __syncthreads();
  if (tid < 5) {
    float v = red[0][tid] + red[1][tid] + red[2][tid] + red[3][tid];
    atomicAdd(accum + tid, v);
  }
  __syncthreads();
  if (tid == 0) {
    __threadfence();
    unsigned old = atomicAdd((unsigned*)(accum + 5), 1u);
    if (old == 703u) {                // 44*16 = 704 blocks
      float np = fmaxf(atomicAdd(accum + 0, 0.f), 1.f);
      float rg = atomicAdd(accum + 1, 0.f);
      float pp = atomicAdd(accum + 2, 0.f);
      float nn = fmaxf(atomicAdd(accum + 3, 0.f), 1.f);
      float nl = atomicAdd(accum + 4, 0.f);
      dout[0] = 0.5f * (pp / np + nl / nn) + 5.f * (rg / (4.f * np));
    }
  }
}

// ---------- launch ----------
extern "C" void kernel_launch(void* const* d_in, const int* in_sizes, int n_in,
                              void* d_out, int out_size, void* d_ws, size_t ws_size,
                              hipStream_t stream) {
  const float* features = (const float*)d_in[0];
  const float* gt_boxes = (const float*)d_in[1];
  const float* w1    = (const float*)d_in[2];
  const float* b1    = (const float*)d_in[3];
  const float* w_cls = (const float*)d_in[4];
  const float* b_cls = (const float*)d_in[5];
  const float* w_box = (const float*)d_in[6];
  const float* b_box = (const float*)d_in[7];
  float* out = (float*)d_out;
  char* ws = (char*)d_ws;

  // ws layout (featT2 chunk-major: 16*16*2704*64 = 44,302,336 B)
  char*           featT2 = ws;                                  // 44,302,336 B
  unsigned short* w2     = (unsigned short*)(ws + 44302336);    //    442,368 B used
  float*          wpart  = (float*)(ws + 44855296);             //  7,077,888 B
  float*          oh     = (float*)(ws + 51933184);             //  7,680,000 B
  float*          beff   = (float*)(ws + 59613184);             //        192 B
  unsigned*       mx     = (unsigned*)(ws + 59613376);          //      1,024 B
  float*          accum  = (float*)(ws + 59614400);             //         32 B

  k1<<<3504, 256, 0, stream>>>(features, featT2, w1, w_cls, w_box, b1, b_cls,
                               b_box, wpart, beff, gt_boxes, mx,
                               (unsigned*)accum);
  k2<<<864, 256, 0, stream>>>(wpart, w2);
  k3<<<512, 256, 0, stream>>>(featT2, (const char*)w2, beff, oh);
  k4<<<dim3(44, 16), 256, 0, stream>>>(gt_boxes, mx, oh, accum, out);
}